// Round 14
// baseline (6499.552 us; speedup 1.0000x reference)
//
#include <hip/hip_runtime.h>

#define B_ 64
#define N_ 512

typedef __attribute__((ext_vector_type(8))) short bf8_t;    // 8 bf16 (4 VGPRs)
typedef __attribute__((ext_vector_type(16))) float f16_t;   // 32x32 MFMA acc
typedef __attribute__((ext_vector_type(4))) float f4v_t;

#define MFMA32(a, b, c) __builtin_amdgcn_mfma_f32_32x32x16_bf16(a, b, c, 0, 0, 0)

__device__ __forceinline__ ushort f2bf(float x) {
  union { float f; unsigned u; } v; v.f = x;
  unsigned r = v.u + 0x7FFFu + ((v.u >> 16) & 1u);   // RNE
  return (ushort)(r >> 16);
}
__device__ __forceinline__ float bf2f(ushort h) {
  union { unsigned u; float f; } v; v.u = ((unsigned)h) << 16;
  return v.f;
}

__device__ __forceinline__ void gld16(const ushort* g, ushort* l) {
  __builtin_amdgcn_global_load_lds(
      (const __attribute__((address_space(1))) unsigned int*)(uintptr_t)g,
      (__attribute__((address_space(3))) unsigned int*)(uintptr_t)l,
      16, 0, 0);
}

// XCD-aware bijective swizzle (nwg must be divisible by 8)
__device__ __forceinline__ int xcd_logical(int nwg) {
  int lin = blockIdx.x + gridDim.x * (blockIdx.y + gridDim.y * blockIdx.z);
  return (lin & 7) * (nwg >> 3) + (lin >> 3);
}

// XOR swizzle (BK=32: 4x 16B slots/row; (r>>1)&3 spread → 2-way = free)
__device__ __forceinline__ int swz32(int r) { return (r >> 1) & 3; }

template <int ROWS, int THREADS>
__device__ __forceinline__ void stage_tile2(const ushort* g, int lda, int k0,
                                            ushort* l, int tid) {
  constexpr int RT = (ROWS * 32) / (THREADS * 8);
#pragma unroll
  for (int q = 0; q < RT; ++q) {
    int e  = q * THREADS * 8 + tid * 8;
    int r  = e >> 5;
    int c8 = (e >> 3) & 3;
    int g8 = c8 ^ swz32(r);
    gld16(g + (size_t)r * lda + k0 + g8 * 8, l + e);
  }
}

// C/D row-within-frag for 32x32: (r&3) + 8*(r>>2) + 4*hb
__device__ __forceinline__ int crow32(int r, int hb) {
  return (r & 3) + 8 * (r >> 2) + 4 * hb;
}

// ---------------------------------------------------------------------------
// 4-tile split-bf16 core (3-term): identity rows (f32-precision results).
// 128x128, 256 thr (2x2 waves).
// ---------------------------------------------------------------------------
__device__ __forceinline__ void core128(
    const ushort* Ah, const ushort* Al, int lda,
    const ushort* Bh, const ushort* Bl, int ldb,
    int K, ushort* lds, f16_t acc[2][2]) {
  constexpr int TILE = 128 * 32;
  constexpr int SSZ  = 4 * TILE;
  const int tid = threadIdx.x, lane = tid & 63, wave = tid >> 6;
  const int ar = lane & 31, hb = lane >> 5;
  const int wm = wave >> 1, wn = wave & 1;

  auto stage = [&](int buf, int k0) {
    ushort* lb = lds + buf * SSZ;
    stage_tile2<128, 256>(Ah, lda, k0, lb, tid);
    stage_tile2<128, 256>(Al, lda, k0, lb + TILE, tid);
    stage_tile2<128, 256>(Bh, ldb, k0, lb + 2 * TILE, tid);
    stage_tile2<128, 256>(Bl, ldb, k0, lb + 3 * TILE, tid);
  };

  const int nc = K >> 5;
  stage(0, 0);
  int buf = 0;
  for (int c = 0; c < nc; ++c) {
    __syncthreads();
    if (c + 1 < nc) stage(buf ^ 1, (c + 1) << 5);
    const ushort* lb = lds + buf * SSZ;
#pragma unroll
    for (int ks = 0; ks < 2; ++ks) {
      bf8_t ah[2], al[2], bh[2], bl[2];
#pragma unroll
      for (int i = 0; i < 2; ++i) {
        int r = wm * 64 + 32 * i + ar;
        int c8 = (ks * 2 + hb) ^ swz32(r);
        ah[i] = *(const bf8_t*)(lb + r * 32 + c8 * 8);
        al[i] = *(const bf8_t*)(lb + TILE + r * 32 + c8 * 8);
      }
#pragma unroll
      for (int j = 0; j < 2; ++j) {
        int r = wn * 64 + 32 * j + ar;
        int c8 = (ks * 2 + hb) ^ swz32(r);
        bh[j] = *(const bf8_t*)(lb + 2 * TILE + r * 32 + c8 * 8);
        bl[j] = *(const bf8_t*)(lb + 3 * TILE + r * 32 + c8 * 8);
      }
#pragma unroll
      for (int i = 0; i < 2; ++i)
#pragma unroll
        for (int j = 0; j < 2; ++j) {
          acc[i][j] = MFMA32(ah[i], bh[j], acc[i][j]);
          acc[i][j] = MFMA32(ah[i], bl[j], acc[i][j]);
          acc[i][j] = MFMA32(al[i], bh[j], acc[i][j]);
        }
    }
    buf ^= 1;
  }
}

// ---------------------------------------------------------------------------
// Generic 2-tile 1-term core: BM x BN, 256 thr (2x2 waves),
// frags (BM/64)x(BN/64) per wave. LDS dbuf = 2*(BM+BN)*32*2 bytes.
// ---------------------------------------------------------------------------
template <int BM, int BN>
__device__ __forceinline__ void core2(
    const ushort* Ah, int lda,
    const ushort* Bh, int ldb,
    int K, ushort* lds, f16_t acc[BM / 64][BN / 64]) {
  constexpr int TA = BM * 32;
  constexpr int SSZ = (BM + BN) * 32;
  constexpr int FI = BM / 64, FJ = BN / 64;
  const int tid = threadIdx.x, lane = tid & 63, wave = tid >> 6;
  const int ar = lane & 31, hb = lane >> 5;
  const int wm = wave >> 1, wn = wave & 1;

  auto stage = [&](int buf, int k0) {
    ushort* lb = lds + buf * SSZ;
    stage_tile2<BM, 256>(Ah, lda, k0, lb, tid);
    stage_tile2<BN, 256>(Bh, ldb, k0, lb + TA, tid);
  };

  const int nc = K >> 5;
  stage(0, 0);
  int buf = 0;
  for (int c = 0; c < nc; ++c) {
    __syncthreads();
    if (c + 1 < nc) stage(buf ^ 1, (c + 1) << 5);
    const ushort* lb = lds + buf * SSZ;
#pragma unroll
    for (int ks = 0; ks < 2; ++ks) {
      bf8_t ah[FI], bh[FJ];
#pragma unroll
      for (int i = 0; i < FI; ++i) {
        int r = wm * (BM / 2) + 32 * i + ar;
        int c8 = (ks * 2 + hb) ^ swz32(r);
        ah[i] = *(const bf8_t*)(lb + r * 32 + c8 * 8);
      }
#pragma unroll
      for (int j = 0; j < FJ; ++j) {
        int r = wn * (BN / 2) + 32 * j + ar;
        int c8 = (ks * 2 + hb) ^ swz32(r);
        bh[j] = *(const bf8_t*)(lb + TA + r * 32 + c8 * 8);
      }
#pragma unroll
      for (int i = 0; i < FI; ++i)
#pragma unroll
        for (int j = 0; j < FJ; ++j)
          acc[i][j] = MFMA32(ah[i], bh[j], acc[i][j]);
    }
    buf ^= 1;
  }
}

// ---------------------------------------------------------------------------
// Prep: S -> Bcat seg0/seg2 (bf16) + STb transposed bf16 copy
// ---------------------------------------------------------------------------
__global__ __launch_bounds__(256) void stb_k(const float* __restrict__ S,
                                             ushort* __restrict__ Bcat,
                                             ushort* __restrict__ STb) {
  __shared__ float tile[16][17];
  int s = blockIdx.z;
  int n0 = blockIdx.y * 16, m0 = blockIdx.x * 16;
  int tx = threadIdx.x & 15, ty = threadIdx.x >> 4;
  float v = S[(size_t)s * 262144 + (size_t)(n0 + ty) * 512 + m0 + tx];
  tile[ty][tx] = v;
  Bcat[(size_t)(n0 + ty) * 2048 + (size_t)(2 * s) * 512 + m0 + tx] = f2bf(v);
  __syncthreads();
  STb[(size_t)s * 262144 + (size_t)(m0 + ty) * 512 + n0 + tx] = f2bf(tile[tx][ty]);
}

// SS = S^2 via 1-term MFMA; writes Bcat seg(2s+1).
__global__ __launch_bounds__(256) void ssqm_k(const ushort* __restrict__ Bc,
                                              const ushort* __restrict__ STb,
                                              ushort* __restrict__ Bout) {
  __shared__ __attribute__((aligned(16))) ushort lds[2 * 2 * 128 * 32];
  int tid = threadIdx.x, lane = tid & 63, wave = tid >> 6;
  int wm = wave >> 1, wn = wave & 1, ar = lane & 31, hb = lane >> 5;
  int a = blockIdx.x, bm = blockIdx.y, s = blockIdx.z;
  f16_t acc[2][2] = {};
  core2<128, 128>(Bc + (size_t)(a * 128) * 2048 + (size_t)(2 * s) * 512, 2048,
                  STb + (size_t)s * 262144 + (size_t)(bm * 128) * 512, 512,
                  512, lds, acc);
#pragma unroll
  for (int i = 0; i < 2; ++i)
#pragma unroll
    for (int j = 0; j < 2; ++j) {
      int m_ = bm * 128 + wn * 64 + 32 * j + ar;
#pragma unroll
      for (int r = 0; r < 16; ++r) {
        int n_ = a * 128 + wm * 64 + 32 * i + crow32(r, hb);
        Bout[(size_t)n_ * 2048 + (size_t)(2 * s + 1) * 512 + m_] = f2bf(acc[i][j][r]);
      }
    }
}

// ---------------------------------------------------------------------------
// One-shot weight prep into packed region. Per-cell layout (ushort offsets):
// [gid_h 16384][gid_l 16384][gd 65536][cid_h 8192][cid_l 8192][cd 32768]
// ---------------------------------------------------------------------------
struct WSrc { const float* wg[4]; const float* wc[4]; };

__global__ __launch_bounds__(256) void wprep_all_k(WSrc src,
                                                   ushort* __restrict__ Wbuf) {
  int idx = blockIdx.x * 256 + threadIdx.x;
  if (idx >= 4 * 147456) return;
  int ci = idx / 147456, r = idx % 147456;
  int C = (ci == 0) ? 66 : (ci == 2) ? 65 : 128;
  const float* WG = src.wg[ci];
  const float* WC = src.wc[ci];
  ushort v;
  if (r < 32768) {                       // gate id hi/lo
    int e = r & 16383, c = e & 127, d = e >> 7;
    float x = (c < C) ? WG[(size_t)c * 128 + d] : 0.f;
    ushort hh = f2bf(x);
    v = (r < 16384) ? hh : f2bf(x - bf2f(hh));
  } else if (r < 98304) {                // gate diff hi
    int e = r - 32768, c = e & 127, i = e >> 7;
    int t = 1 + (i >> 7), d = i & 127;
    v = (c < C) ? f2bf(WG[(size_t)(t * C + c) * 128 + d]) : (ushort)0;
  } else if (r < 114688) {               // cand id hi/lo
    int e = (r - 98304) & 8191, c = e & 127, d = e >> 7;
    float x = (c < C) ? WC[(size_t)c * 64 + d] : 0.f;
    ushort hh = f2bf(x);
    v = (r < 106496) ? hh : f2bf(x - bf2f(hh));
  } else {                               // cand diff hi
    int e = r - 114688, c = e & 127, i = e >> 7;
    int t = 1 + (i >> 6), d = i & 63;
    v = (c < C) ? f2bf(WC[(size_t)(t * C + c) * 64 + d]) : (ushort)0;
  }
  Wbuf[idx] = v;
}

// ---------------------------------------------------------------------------
// Pack zT[(b,n)][c] = [x | h | 0-pad], split hi/lo. hT is [(b,n)][d].
// xmode 0: inputs gather (t); xmode 1: flat [jg]; xmode 2: hT-row layout
// ---------------------------------------------------------------------------
__global__ __launch_bounds__(256) void packzT_k(const float* __restrict__ xsrc,
                                                int xmode, int t, int Cx, int C,
                                                const float* __restrict__ hT,
                                                ushort* __restrict__ Zh,
                                                ushort* __restrict__ Zl) {
  int jg = blockIdx.x * 256 + threadIdx.x;   // b*512 + n
  int b = jg >> 9, n = jg & 511;
  for (int c0 = 0; c0 < 128; c0 += 8) {
    bf8_t vh, vl;
#pragma unroll
    for (int q = 0; q < 8; ++q) {
      int c = c0 + q;
      float v;
      if (c < Cx) {
        if (xmode == 0)      v = xsrc[((size_t)(b * Cx + c) * 512 + n) * 12 + t];
        else if (xmode == 1) v = xsrc[jg];
        else                 v = xsrc[(size_t)jg * 64 + c];
      } else if (c < C) {
        v = hT[(size_t)jg * 64 + (c - Cx)];
      } else {
        v = 0.f;
      }
      ushort hh = f2bf(v);
      vh[q] = (short)hh;
      vl[q] = (short)f2bf(v - bf2f(hh));
    }
    *(bf8_t*)(Zh + (size_t)jg * 128 + c0) = vh;
    *(bf8_t*)(Zl + (size_t)jg * 128 + c0) = vl;
  }
}

// ---------------------------------------------------------------------------
// Combined g1: mt < NMT -> 1-term diffusion rows (bf16 Gh);
// mt == NMT -> 3-term identity rows (f32 G0T).
// MODE 0: DR=128 gate, NMT=4; MODE 1: DR=64 cand, NMT=2.
// ---------------------------------------------------------------------------
template <int MODE>
__global__ __launch_bounds__(256, 2) void g1_k(const ushort* __restrict__ Wih,
                                               const ushort* __restrict__ Wil,
                                               const ushort* __restrict__ Wd,
                                               const ushort* __restrict__ Zh,
                                               const ushort* __restrict__ Zl,
                                               ushort* __restrict__ Gh,
                                               float* __restrict__ G0T, int K) {
  __shared__ __attribute__((aligned(16))) ushort lds[2 * 4 * 128 * 32];
  constexpr int DR = (MODE == 0) ? 128 : 64;
  constexpr int NMT = (MODE == 0) ? 4 : 2;
  int tid = threadIdx.x, lane = tid & 63, wave = tid >> 6;
  int wm = wave >> 1, wn = wave & 1, ar = lane & 31, hb = lane >> 5;
  int L = xcd_logical(256 * (NMT + 1));
  int mt = L % (NMT + 1), nt = L / (NMT + 1);
  f16_t acc[2][2] = {};
  if (mt == NMT) {
    core128(Wih, Wil, 128,
            Zh + (size_t)nt * 128 * 128, Zl + (size_t)nt * 128 * 128, 128,
            K, lds, acc);
#pragma unroll
    for (int i = 0; i < 2; ++i)
#pragma unroll
      for (int j = 0; j < 2; ++j) {
        int jg = nt * 128 + wn * 64 + 32 * j + ar;
#pragma unroll
        for (int r = 0; r < 16; ++r) {
          int d = wm * 64 + 32 * i + crow32(r, hb);
          if (d >= DR) continue;
          G0T[(size_t)jg * DR + d] = acc[i][j][r];
        }
      }
  } else {
    core2<128, 128>(Wd + (size_t)mt * 128 * 128, 128,
                    Zh + (size_t)nt * 128 * 128, 128,
                    K, lds, acc);
#pragma unroll
    for (int i = 0; i < 2; ++i)
#pragma unroll
      for (int j = 0; j < 2; ++j) {
        int jg = nt * 128 + wn * 64 + 32 * j + ar;
        int b = jg >> 9, m = jg & 511;
#pragma unroll
        for (int r = 0; r < 16; ++r) {
          int ii = mt * 128 + wm * 64 + 32 * i + crow32(r, hb);
          int tt = ii / DR, d = ii % DR;
          Gh[((size_t)(b * DR + d)) * 2048 + (size_t)tt * 512 + m] = f2bf(acc[i][j][r]);
        }
      }
  }
}

// ---------------------------------------------------------------------------
// Fused gate diffusion: BM=64 x BN=128, kz=1 (full K=2048), grid 512.
// b = nt; epilogue: sigmoid(+G0T+bg); d<64 -> r*h into zT; d>=64 -> u into U.
// ---------------------------------------------------------------------------
__global__ __launch_bounds__(256, 2) void ru1fused_k(const ushort* __restrict__ Gh,
                                                     const ushort* __restrict__ Bch,
                                                     const float* __restrict__ G0T,
                                                     const float* __restrict__ bg,
                                                     const float* __restrict__ hT,
                                                     float* __restrict__ U,
                                                     ushort* __restrict__ Zh,
                                                     ushort* __restrict__ Zl,
                                                     int Cx) {
  __shared__ __attribute__((aligned(16))) ushort lds[2 * (64 + 128) * 32];
  int tid = threadIdx.x, lane = tid & 63, wave = tid >> 6;
  int wm = wave >> 1, wn = wave & 1, ar = lane & 31, hb = lane >> 5;
  int L = xcd_logical(512);
  int mt = L & 7, nt = L >> 3;     // mt-fastest: 8 sharers of G tile per XCD
  f16_t acc[1][2] = {};
  core2<64, 128>(Bch + (size_t)mt * 64 * 2048, 2048,
                 Gh + (size_t)nt * 128 * 2048, 2048,
                 2048, lds, acc);
#pragma unroll
  for (int j = 0; j < 2; ++j) {
    int d = wn * 64 + 32 * j + ar;
    float bgd = bg[d];
#pragma unroll
    for (int r = 0; r < 16; ++r) {
      int node = mt * 64 + wm * 32 + crow32(r, hb);
      size_t row = (size_t)nt * 512 + node;
      float s = 1.f / (1.f + expf(-(acc[0][j][r] + G0T[row * 128 + d] + bgd)));
      if (d < 64) {
        float rh = s * hT[row * 64 + d];
        ushort hh = f2bf(rh);
        Zh[row * 128 + Cx + d] = hh;
        Zl[row * 128 + Cx + d] = f2bf(rh - bf2f(hh));
      } else {
        U[row * 64 + (d - 64)] = s;
      }
    }
  }
}

// ---------------------------------------------------------------------------
// Fused cand diffusion: BM=64 x BN=64, kz=1, grid 512. b = nt.
// epilogue: c~ = tanh(+G0c+bc); h = u*h + (1-u)*c~.
// ---------------------------------------------------------------------------
__global__ __launch_bounds__(256, 2) void ru2fused_k(const ushort* __restrict__ Gh,
                                                     const ushort* __restrict__ Bch,
                                                     const float* __restrict__ G0c,
                                                     const float* __restrict__ bc,
                                                     const float* __restrict__ U,
                                                     float* __restrict__ hT) {
  __shared__ __attribute__((aligned(16))) ushort lds[2 * (64 + 64) * 32];
  int tid = threadIdx.x, lane = tid & 63, wave = tid >> 6;
  int wm = wave >> 1, wn = wave & 1, ar = lane & 31, hb = lane >> 5;
  int L = xcd_logical(512);
  int mt = L & 7, nt = L >> 3;
  f16_t acc[1][1] = {};
  core2<64, 64>(Bch + (size_t)mt * 64 * 2048, 2048,
                Gh + (size_t)nt * 64 * 2048, 2048,
                2048, lds, acc);
  int d = wn * 32 + ar;
  float bcd = bc[d];
#pragma unroll
  for (int r = 0; r < 16; ++r) {
    int node = mt * 64 + wm * 32 + crow32(r, hb);
    size_t row = (size_t)nt * 512 + node;
    size_t ix = row * 64 + d;
    float ct = tanhf(acc[0][0][r] + G0c[ix] + bcd);
    float u = U[ix];
    hT[ix] = u * hT[ix] + (1.f - u) * ct;
  }
}

__global__ __launch_bounds__(256) void proj_out_k(const float* __restrict__ h1T,
                                                  const float* __restrict__ pw,
                                                  const float* __restrict__ pb,
                                                  float* __restrict__ ybuf,
                                                  float* __restrict__ out, int k) {
  int idx = blockIdx.x * blockDim.x + threadIdx.x;
  if (idx >= B_ * N_) return;
  float s = pb[0];
  const float* hrow = h1T + (size_t)idx * 64;
#pragma unroll
  for (int j = 0; j < 64; ++j)
    s = fmaf(pw[j], hrow[j], s);
  ybuf[idx] = s;
  out[(size_t)idx * 12 + k] = s;
}

extern "C" void kernel_launch(void* const* d_in, const int* in_sizes, int n_in,
                              void* d_out, int out_size, void* d_ws, size_t ws_size,
                              hipStream_t stream) {
  const float* inputs   = (const float*)d_in[0];
  const float* supports = (const float*)d_in[1];
  WSrc wsrc;
  wsrc.wg[0] = (const float*)d_in[2];  wsrc.wg[1] = (const float*)d_in[6];
  wsrc.wg[2] = (const float*)d_in[10]; wsrc.wg[3] = (const float*)d_in[14];
  wsrc.wc[0] = (const float*)d_in[4];  wsrc.wc[1] = (const float*)d_in[8];
  wsrc.wc[2] = (const float*)d_in[12]; wsrc.wc[3] = (const float*)d_in[16];
  const float* Bg[4] = { (const float*)d_in[3],  (const float*)d_in[7],
                         (const float*)d_in[11], (const float*)d_in[15] };
  const float* Bc[4] = { (const float*)d_in[5],  (const float*)d_in[9],
                         (const float*)d_in[13], (const float*)d_in[17] };
  const float* proj_w = (const float*)d_in[18];
  const float* proj_b = (const float*)d_in[19];
  float* out = (float*)d_out;

  char* p = (char*)d_ws;
  auto carve = [&](size_t bytes) { void* q = p; p += (bytes + 255) & ~(size_t)255; return q; };
  ushort* Bch  = (ushort*)carve((size_t)512 * 2048 * 2);
  ushort* zTh  = (ushort*)carve((size_t)32768 * 128 * 2);
  ushort* zTl  = (ushort*)carve((size_t)32768 * 128 * 2);
  ushort* Gh   = (ushort*)carve((size_t)8192 * 2048 * 2);
  float*  G0T  = (float*)carve((size_t)32768 * 128 * 4);
  float*  U    = (float*)carve((size_t)2097152 * 4);
  float*  h0   = (float*)carve((size_t)2097152 * 4);
  float*  h1   = (float*)carve((size_t)2097152 * 4);
  float*  ybuf = (float*)carve((size_t)B_ * N_ * 4);
  ushort* Wbuf = (ushort*)carve((size_t)4 * 147456 * 2);
  ushort* STb  = (ushort*)U;     // overlay: STb (1MB) only needed during prep

  // h0 + h1 + ybuf contiguous -> one memset
  hipMemsetAsync(h0, 0, (size_t)2097152 * 4 * 2 + (size_t)B_ * N_ * 4, stream);

  stb_k<<<dim3(32, 32, 2), 256, 0, stream>>>(supports, Bch, STb);
  ssqm_k<<<dim3(4, 4, 2), 256, 0, stream>>>(Bch, STb, Bch);
  wprep_all_k<<<(4 * 147456 + 255) / 256, 256, 0, stream>>>(wsrc, Wbuf);

  auto cell = [&](int ci, int Cx, const float* x, int xmode, int t, float* h) {
    int C = Cx + 64;
    int K1 = (C + 31) & ~31;   // 96 or 128
    ushort* cw = Wbuf + (size_t)ci * 147456;
    ushort* Wgid_h = cw;          ushort* Wgid_l = cw + 16384;
    ushort* Wgd    = cw + 32768;
    ushort* Wcid_h = cw + 98304;  ushort* Wcid_l = cw + 106496;
    ushort* Wcd    = cw + 114688;
    packzT_k<<<128, 256, 0, stream>>>(x, xmode, t, Cx, C, h, zTh, zTl);
    g1_k<0><<<dim3(256, 5), 256, 0, stream>>>(Wgid_h, Wgid_l, Wgd, zTh, zTl, Gh, G0T, K1);
    ru1fused_k<<<512, 256, 0, stream>>>(Gh, Bch, G0T, Bg[ci], h, U, zTh, zTl, Cx);
    g1_k<1><<<dim3(256, 3), 256, 0, stream>>>(Wcid_h, Wcid_l, Wcd, zTh, zTl, Gh, G0T, K1);
    ru2fused_k<<<512, 256, 0, stream>>>(Gh, Bch, G0T, Bc[ci], U, h);
  };

  for (int t = 0; t < 12; ++t) {
    cell(0, 2, inputs, 0, t, h0);
    cell(1, 64, h0, 2, 0, h1);
  }
  for (int k = 0; k < 12; ++k) {
    cell(2, 1, ybuf, 1, 0, h0);
    cell(3, 64, h0, 2, 0, h1);
    proj_out_k<<<(B_ * N_ + 255) / 256, 256, 0, stream>>>(h1, proj_w, proj_b, ybuf, out, k);
  }
}

// Round 15
// 6229.366 us; speedup vs baseline: 1.0434x; 1.0434x over previous
//
#include <hip/hip_runtime.h>

#define B_ 64
#define N_ 512

typedef __attribute__((ext_vector_type(8))) short bf8_t;    // 8 bf16 (4 VGPRs)
typedef __attribute__((ext_vector_type(16))) float f16_t;   // 32x32 MFMA acc
typedef __attribute__((ext_vector_type(4))) float f4v_t;

#define MFMA32(a, b, c) __builtin_amdgcn_mfma_f32_32x32x16_bf16(a, b, c, 0, 0, 0)

__device__ __forceinline__ ushort f2bf(float x) {
  union { float f; unsigned u; } v; v.f = x;
  unsigned r = v.u + 0x7FFFu + ((v.u >> 16) & 1u);   // RNE
  return (ushort)(r >> 16);
}
__device__ __forceinline__ float bf2f(ushort h) {
  union { unsigned u; float f; } v; v.u = ((unsigned)h) << 16;
  return v.f;
}

__device__ __forceinline__ void gld16(const ushort* g, ushort* l) {
  __builtin_amdgcn_global_load_lds(
      (const __attribute__((address_space(1))) unsigned int*)(uintptr_t)g,
      (__attribute__((address_space(3))) unsigned int*)(uintptr_t)l,
      16, 0, 0);
}

// XCD-aware bijective swizzle (nwg must be divisible by 8)
__device__ __forceinline__ int xcd_logical(int nwg) {
  int lin = blockIdx.x + gridDim.x * (blockIdx.y + gridDim.y * blockIdx.z);
  return (lin & 7) * (nwg >> 3) + (lin >> 3);
}

// XOR swizzle (BK=32: 4x 16B slots/row; (r>>1)&3 spread → 2-way = free)
__device__ __forceinline__ int swz32(int r) { return (r >> 1) & 3; }

template <int ROWS, int THREADS>
__device__ __forceinline__ void stage_tile2(const ushort* g, int lda, int k0,
                                            ushort* l, int tid) {
  constexpr int RT = (ROWS * 32) / (THREADS * 8);
#pragma unroll
  for (int q = 0; q < RT; ++q) {
    int e  = q * THREADS * 8 + tid * 8;
    int r  = e >> 5;
    int c8 = (e >> 3) & 3;
    int g8 = c8 ^ swz32(r);
    gld16(g + (size_t)r * lda + k0 + g8 * 8, l + e);
  }
}

// C/D row-within-frag for 32x32: (r&3) + 8*(r>>2) + 4*hb
__device__ __forceinline__ int crow32(int r, int hb) {
  return (r & 3) + 8 * (r >> 2) + 4 * hb;
}

// ---------------------------------------------------------------------------
// 4-tile split-bf16 core (3-term): identity rows (f32-precision results).
// 128x128, 256 thr (2x2 waves).
// ---------------------------------------------------------------------------
__device__ __forceinline__ void core128(
    const ushort* Ah, const ushort* Al, int lda,
    const ushort* Bh, const ushort* Bl, int ldb,
    int K, ushort* lds, f16_t acc[2][2]) {
  constexpr int TILE = 128 * 32;
  constexpr int SSZ  = 4 * TILE;
  const int tid = threadIdx.x, lane = tid & 63, wave = tid >> 6;
  const int ar = lane & 31, hb = lane >> 5;
  const int wm = wave >> 1, wn = wave & 1;

  auto stage = [&](int buf, int k0) {
    ushort* lb = lds + buf * SSZ;
    stage_tile2<128, 256>(Ah, lda, k0, lb, tid);
    stage_tile2<128, 256>(Al, lda, k0, lb + TILE, tid);
    stage_tile2<128, 256>(Bh, ldb, k0, lb + 2 * TILE, tid);
    stage_tile2<128, 256>(Bl, ldb, k0, lb + 3 * TILE, tid);
  };

  const int nc = K >> 5;
  stage(0, 0);
  int buf = 0;
  for (int c = 0; c < nc; ++c) {
    __syncthreads();
    if (c + 1 < nc) stage(buf ^ 1, (c + 1) << 5);
    const ushort* lb = lds + buf * SSZ;
#pragma unroll
    for (int ks = 0; ks < 2; ++ks) {
      bf8_t ah[2], al[2], bh[2], bl[2];
#pragma unroll
      for (int i = 0; i < 2; ++i) {
        int r = wm * 64 + 32 * i + ar;
        int c8 = (ks * 2 + hb) ^ swz32(r);
        ah[i] = *(const bf8_t*)(lb + r * 32 + c8 * 8);
        al[i] = *(const bf8_t*)(lb + TILE + r * 32 + c8 * 8);
      }
#pragma unroll
      for (int j = 0; j < 2; ++j) {
        int r = wn * 64 + 32 * j + ar;
        int c8 = (ks * 2 + hb) ^ swz32(r);
        bh[j] = *(const bf8_t*)(lb + 2 * TILE + r * 32 + c8 * 8);
        bl[j] = *(const bf8_t*)(lb + 3 * TILE + r * 32 + c8 * 8);
      }
#pragma unroll
      for (int i = 0; i < 2; ++i)
#pragma unroll
        for (int j = 0; j < 2; ++j) {
          acc[i][j] = MFMA32(ah[i], bh[j], acc[i][j]);
          acc[i][j] = MFMA32(ah[i], bl[j], acc[i][j]);
          acc[i][j] = MFMA32(al[i], bh[j], acc[i][j]);
        }
    }
    buf ^= 1;
  }
}

// ---------------------------------------------------------------------------
// 2-tile core (1-term pure bf16), 128x128, 32KB LDS dbuf.
// ---------------------------------------------------------------------------
__device__ __forceinline__ void core128_1(
    const ushort* Ah, int lda,
    const ushort* Bh, int ldb,
    int K, ushort* lds, f16_t acc[2][2]) {
  constexpr int TILE = 128 * 32;
  constexpr int SSZ  = 2 * TILE;
  const int tid = threadIdx.x, lane = tid & 63, wave = tid >> 6;
  const int ar = lane & 31, hb = lane >> 5;
  const int wm = wave >> 1, wn = wave & 1;

  auto stage = [&](int buf, int k0) {
    ushort* lb = lds + buf * SSZ;
    stage_tile2<128, 256>(Ah, lda, k0, lb, tid);
    stage_tile2<128, 256>(Bh, ldb, k0, lb + TILE, tid);
  };

  const int nc = K >> 5;
  stage(0, 0);
  int buf = 0;
  for (int c = 0; c < nc; ++c) {
    __syncthreads();
    if (c + 1 < nc) stage(buf ^ 1, (c + 1) << 5);
    const ushort* lb = lds + buf * SSZ;
#pragma unroll
    for (int ks = 0; ks < 2; ++ks) {
      bf8_t ah[2], bh[2];
#pragma unroll
      for (int i = 0; i < 2; ++i) {
        int r = wm * 64 + 32 * i + ar;
        int c8 = (ks * 2 + hb) ^ swz32(r);
        ah[i] = *(const bf8_t*)(lb + r * 32 + c8 * 8);
      }
#pragma unroll
      for (int j = 0; j < 2; ++j) {
        int r = wn * 64 + 32 * j + ar;
        int c8 = (ks * 2 + hb) ^ swz32(r);
        bh[j] = *(const bf8_t*)(lb + TILE + r * 32 + c8 * 8);
      }
#pragma unroll
      for (int i = 0; i < 2; ++i)
#pragma unroll
        for (int j = 0; j < 2; ++j)
          acc[i][j] = MFMA32(ah[i], bh[j], acc[i][j]);
    }
    buf ^= 1;
  }
}

// ---------------------------------------------------------------------------
// Prep: S -> Bcat seg0/seg2 (bf16) + STb transposed bf16 copy
// ---------------------------------------------------------------------------
__global__ __launch_bounds__(256) void stb_k(const float* __restrict__ S,
                                             ushort* __restrict__ Bcat,
                                             ushort* __restrict__ STb) {
  __shared__ float tile[16][17];
  int s = blockIdx.z;
  int n0 = blockIdx.y * 16, m0 = blockIdx.x * 16;
  int tx = threadIdx.x & 15, ty = threadIdx.x >> 4;
  float v = S[(size_t)s * 262144 + (size_t)(n0 + ty) * 512 + m0 + tx];
  tile[ty][tx] = v;
  Bcat[(size_t)(n0 + ty) * 2048 + (size_t)(2 * s) * 512 + m0 + tx] = f2bf(v);
  __syncthreads();
  STb[(size_t)s * 262144 + (size_t)(m0 + ty) * 512 + n0 + tx] = f2bf(tile[tx][ty]);
}

// SS = S^2 via 1-term MFMA; writes Bcat seg(2s+1).
__global__ __launch_bounds__(256) void ssqm_k(const ushort* __restrict__ Bc,
                                              const ushort* __restrict__ STb,
                                              ushort* __restrict__ Bout) {
  __shared__ __attribute__((aligned(16))) ushort lds[2 * 2 * 128 * 32];
  int tid = threadIdx.x, lane = tid & 63, wave = tid >> 6;
  int wm = wave >> 1, wn = wave & 1, ar = lane & 31, hb = lane >> 5;
  int a = blockIdx.x, bm = blockIdx.y, s = blockIdx.z;
  f16_t acc[2][2] = {};
  core128_1(Bc + (size_t)(a * 128) * 2048 + (size_t)(2 * s) * 512, 2048,
            STb + (size_t)s * 262144 + (size_t)(bm * 128) * 512, 512,
            512, lds, acc);
#pragma unroll
  for (int i = 0; i < 2; ++i)
#pragma unroll
    for (int j = 0; j < 2; ++j) {
      int m_ = bm * 128 + wn * 64 + 32 * j + ar;
#pragma unroll
      for (int r = 0; r < 16; ++r) {
        int n_ = a * 128 + wm * 64 + 32 * i + crow32(r, hb);
        Bout[(size_t)n_ * 2048 + (size_t)(2 * s + 1) * 512 + m_] = f2bf(acc[i][j][r]);
      }
    }
}

// ---------------------------------------------------------------------------
// One-shot weight prep into packed region. Per-cell layout (ushort offsets):
// [gid_h 16384][gid_l 16384][gd 65536][cid_h 8192][cid_l 8192][cd 32768]
// ---------------------------------------------------------------------------
struct WSrc { const float* wg[4]; const float* wc[4]; };

__global__ __launch_bounds__(256) void wprep_all_k(WSrc src,
                                                   ushort* __restrict__ Wbuf) {
  int idx = blockIdx.x * 256 + threadIdx.x;
  if (idx >= 4 * 147456) return;
  int ci = idx / 147456, r = idx % 147456;
  int C = (ci == 0) ? 66 : (ci == 2) ? 65 : 128;
  const float* WG = src.wg[ci];
  const float* WC = src.wc[ci];
  ushort v;
  if (r < 32768) {                       // gate id hi/lo
    int e = r & 16383, c = e & 127, d = e >> 7;
    float x = (c < C) ? WG[(size_t)c * 128 + d] : 0.f;
    ushort hh = f2bf(x);
    v = (r < 16384) ? hh : f2bf(x - bf2f(hh));
  } else if (r < 98304) {                // gate diff hi
    int e = r - 32768, c = e & 127, i = e >> 7;
    int t = 1 + (i >> 7), d = i & 127;
    v = (c < C) ? f2bf(WG[(size_t)(t * C + c) * 128 + d]) : (ushort)0;
  } else if (r < 114688) {               // cand id hi/lo
    int e = (r - 98304) & 8191, c = e & 127, d = e >> 7;
    float x = (c < C) ? WC[(size_t)c * 64 + d] : 0.f;
    ushort hh = f2bf(x);
    v = (r < 106496) ? hh : f2bf(x - bf2f(hh));
  } else {                               // cand diff hi
    int e = r - 114688, c = e & 127, i = e >> 7;
    int t = 1 + (i >> 6), d = i & 63;
    v = (c < C) ? f2bf(WC[(size_t)(t * C + c) * 64 + d]) : (ushort)0;
  }
  Wbuf[idx] = v;
}

// ---------------------------------------------------------------------------
// Pack zT[(b,n)][c] = [x | h | 0-pad], split hi/lo. hT is [(b,n)][d].
// xmode 0: inputs gather (t); xmode 1: flat [jg]; xmode 2: hT-row layout
// ---------------------------------------------------------------------------
__global__ __launch_bounds__(256) void packzT_k(const float* __restrict__ xsrc,
                                                int xmode, int t, int Cx, int C,
                                                const float* __restrict__ hT,
                                                ushort* __restrict__ Zh,
                                                ushort* __restrict__ Zl) {
  int jg = blockIdx.x * 256 + threadIdx.x;   // b*512 + n
  int b = jg >> 9, n = jg & 511;
  for (int c0 = 0; c0 < 128; c0 += 8) {
    bf8_t vh, vl;
#pragma unroll
    for (int q = 0; q < 8; ++q) {
      int c = c0 + q;
      float v;
      if (c < Cx) {
        if (xmode == 0)      v = xsrc[((size_t)(b * Cx + c) * 512 + n) * 12 + t];
        else if (xmode == 1) v = xsrc[jg];
        else                 v = xsrc[(size_t)jg * 64 + c];
      } else if (c < C) {
        v = hT[(size_t)jg * 64 + (c - Cx)];
      } else {
        v = 0.f;
      }
      ushort hh = f2bf(v);
      vh[q] = (short)hh;
      vl[q] = (short)f2bf(v - bf2f(hh));
    }
    *(bf8_t*)(Zh + (size_t)jg * 128 + c0) = vh;
    *(bf8_t*)(Zl + (size_t)jg * 128 + c0) = vl;
  }
}

// ---------------------------------------------------------------------------
// Combined g1: mt < NMT -> 1-term diffusion rows (bf16 Gh);
// mt == NMT -> 3-term identity rows (f32 G0T).
// MODE 0: DR=128 gate, NMT=4; MODE 1: DR=64 cand, NMT=2.
// ---------------------------------------------------------------------------
template <int MODE>
__global__ __launch_bounds__(256, 2) void g1_k(const ushort* __restrict__ Wih,
                                               const ushort* __restrict__ Wil,
                                               const ushort* __restrict__ Wd,
                                               const ushort* __restrict__ Zh,
                                               const ushort* __restrict__ Zl,
                                               ushort* __restrict__ Gh,
                                               float* __restrict__ G0T, int K) {
  __shared__ __attribute__((aligned(16))) ushort lds[2 * 4 * 128 * 32];
  constexpr int DR = (MODE == 0) ? 128 : 64;
  constexpr int NMT = (MODE == 0) ? 4 : 2;
  int tid = threadIdx.x, lane = tid & 63, wave = tid >> 6;
  int wm = wave >> 1, wn = wave & 1, ar = lane & 31, hb = lane >> 5;
  int L = xcd_logical(256 * (NMT + 1));
  int mt = L % (NMT + 1), nt = L / (NMT + 1);
  f16_t acc[2][2] = {};
  if (mt == NMT) {
    core128(Wih, Wil, 128,
            Zh + (size_t)nt * 128 * 128, Zl + (size_t)nt * 128 * 128, 128,
            K, lds, acc);
#pragma unroll
    for (int i = 0; i < 2; ++i)
#pragma unroll
      for (int j = 0; j < 2; ++j) {
        int jg = nt * 128 + wn * 64 + 32 * j + ar;
#pragma unroll
        for (int r = 0; r < 16; ++r) {
          int d = wm * 64 + 32 * i + crow32(r, hb);
          if (d >= DR) continue;
          G0T[(size_t)jg * DR + d] = acc[i][j][r];
        }
      }
  } else {
    core128_1(Wd + (size_t)mt * 128 * 128, 128,
              Zh + (size_t)nt * 128 * 128, 128,
              K, lds, acc);
#pragma unroll
    for (int i = 0; i < 2; ++i)
#pragma unroll
      for (int j = 0; j < 2; ++j) {
        int jg = nt * 128 + wn * 64 + 32 * j + ar;
        int b = jg >> 9, m = jg & 511;
#pragma unroll
        for (int r = 0; r < 16; ++r) {
          int ii = mt * 128 + wm * 64 + 32 * i + crow32(r, hb);
          int tt = ii / DR, d = ii % DR;
          Gh[((size_t)(b * DR + d)) * 2048 + (size_t)tt * 512 + m] = f2bf(acc[i][j][r]);
        }
      }
  }
}

// ---------------------------------------------------------------------------
// Gate diffusion GEMM (1-term, 2-tile), split-K kz=3 (768/768/512): -> P
// ---------------------------------------------------------------------------
__global__ __launch_bounds__(256, 3) void ru1g_k(const ushort* __restrict__ Gh,
                                                 const ushort* __restrict__ Bch,
                                                 float* __restrict__ P) {
  __shared__ __attribute__((aligned(16))) ushort lds[2 * 2 * 128 * 32];
  int tid = threadIdx.x, lane = tid & 63, wave = tid >> 6;
  int wm = wave >> 1, wn = wave & 1, ar = lane & 31, hb = lane >> 5;
  int L = xcd_logical(768);
  int mt = L & 3, nt = (L >> 2) & 63, kz = L >> 8;   // kz 0..2
  int k0 = kz * 768;
  int K  = (kz == 2) ? 512 : 768;
  f16_t acc[2][2] = {};
  core128_1(Bch + (size_t)mt * 128 * 2048 + k0, 2048,
            Gh + (size_t)nt * 128 * 2048 + k0, 2048,
            K, lds, acc);
  float* Pz = P + (size_t)kz * 4194304;
#pragma unroll
  for (int i = 0; i < 2; ++i)
#pragma unroll
    for (int j = 0; j < 2; ++j) {
      int R = nt * 128 + wn * 64 + 32 * j + ar;
      int b = R >> 7, d = R & 127;
#pragma unroll
      for (int r = 0; r < 16; ++r) {
        int node = mt * 128 + wm * 64 + 32 * i + crow32(r, hb);
        Pz[((size_t)b * 512 + node) * 128 + d] = acc[i][j][r];
      }
    }
}

// finish gate: sigmoid(P0+P1+P2+G0T+bg); d<64 -> r*h into zT; d>=64 -> u into U
__global__ __launch_bounds__(256) void ru1f_k(const float* __restrict__ P,
                                              const float* __restrict__ G0T,
                                              const float* __restrict__ bg,
                                              const float* __restrict__ hT,
                                              float* __restrict__ U,
                                              ushort* __restrict__ Zh,
                                              ushort* __restrict__ Zl, int Cx) {
  int i4 = blockIdx.x * 256 + threadIdx.x;
  if (i4 >= 1048576) return;
  int base = i4 * 4;
  int row = base >> 7, d = base & 127;
  f4v_t p0 = *(const f4v_t*)(P + base);
  f4v_t p1 = *(const f4v_t*)(P + 4194304 + base);
  f4v_t p2 = *(const f4v_t*)(P + 2 * 4194304 + base);
  f4v_t g0 = *(const f4v_t*)(G0T + base);
  if (d < 64) {
    f4v_t hv = *(const f4v_t*)(hT + (size_t)row * 64 + d);
#pragma unroll
    for (int e = 0; e < 4; ++e) {
      float s = 1.f / (1.f + expf(-(p0[e] + p1[e] + p2[e] + g0[e] + bg[d + e])));
      float rh = s * hv[e];
      ushort hh = f2bf(rh);
      Zh[(size_t)row * 128 + Cx + d + e] = hh;
      Zl[(size_t)row * 128 + Cx + d + e] = f2bf(rh - bf2f(hh));
    }
  } else {
    f4v_t uo;
#pragma unroll
    for (int e = 0; e < 4; ++e)
      uo[e] = 1.f / (1.f + expf(-(p0[e] + p1[e] + p2[e] + g0[e] + bg[d + e])));
    *(f4v_t*)(U + (size_t)row * 64 + (d - 64)) = uo;
  }
}

// ---------------------------------------------------------------------------
// Cand diffusion GEMM (1-term, 2-tile), split-K kz=4.
// ---------------------------------------------------------------------------
__global__ __launch_bounds__(256, 3) void ru2g_k(const ushort* __restrict__ Gh,
                                                 const ushort* __restrict__ Bch,
                                                 float* __restrict__ P) {
  __shared__ __attribute__((aligned(16))) ushort lds[2 * 2 * 128 * 32];
  int tid = threadIdx.x, lane = tid & 63, wave = tid >> 6;
  int wm = wave >> 1, wn = wave & 1, ar = lane & 31, hb = lane >> 5;
  int L = xcd_logical(512);
  int mt = L & 3, nt = (L >> 2) & 31, kz = L >> 7;
  f16_t acc[2][2] = {};
  core128_1(Bch + (size_t)mt * 128 * 2048 + kz * 512, 2048,
            Gh + (size_t)nt * 128 * 2048 + kz * 512, 2048,
            512, lds, acc);
  float* Pz = P + (size_t)kz * 2097152;
#pragma unroll
  for (int i = 0; i < 2; ++i)
#pragma unroll
    for (int j = 0; j < 2; ++j) {
      int R = nt * 128 + wn * 64 + 32 * j + ar;
      int b = R >> 6, d = R & 63;
#pragma unroll
      for (int r = 0; r < 16; ++r) {
        int node = mt * 128 + wm * 64 + 32 * i + crow32(r, hb);
        Pz[((size_t)b * 512 + node) * 64 + d] = acc[i][j][r];
      }
    }
}

// finish cand: c~ = tanh(sum P + G0c + bc); h = u*h + (1-u)*c~
__global__ __launch_bounds__(256) void ru2f_k(const float* __restrict__ P,
                                              const float* __restrict__ G0c,
                                              const float* __restrict__ bc,
                                              const float* __restrict__ U,
                                              float* __restrict__ hT) {
  int i4 = blockIdx.x * 256 + threadIdx.x;
  if (i4 >= 524288) return;
  int base = i4 * 4;
  int d = base & 63;
  f4v_t p0 = *(const f4v_t*)(P + base);
  f4v_t p1 = *(const f4v_t*)(P + 2097152 + base);
  f4v_t p2 = *(const f4v_t*)(P + 2 * 2097152 + base);
  f4v_t p3 = *(const f4v_t*)(P + 3 * 2097152 + base);
  f4v_t g0 = *(const f4v_t*)(G0c + base);
  f4v_t uv = *(const f4v_t*)(U + base);
  f4v_t hv = *(const f4v_t*)(hT + base);
#pragma unroll
  for (int e = 0; e < 4; ++e) {
    float ct = tanhf(p0[e] + p1[e] + p2[e] + p3[e] + g0[e] + bc[d + e]);
    hv[e] = uv[e] * hv[e] + (1.f - uv[e]) * ct;
  }
  *(f4v_t*)(hT + base) = hv;
}

__global__ __launch_bounds__(256) void proj_out_k(const float* __restrict__ h1T,
                                                  const float* __restrict__ pw,
                                                  const float* __restrict__ pb,
                                                  float* __restrict__ ybuf,
                                                  float* __restrict__ out, int k) {
  int idx = blockIdx.x * blockDim.x + threadIdx.x;
  if (idx >= B_ * N_) return;
  float s = pb[0];
  const float* hrow = h1T + (size_t)idx * 64;
#pragma unroll
  for (int j = 0; j < 64; ++j)
    s = fmaf(pw[j], hrow[j], s);
  ybuf[idx] = s;
  out[(size_t)idx * 12 + k] = s;
}

extern "C" void kernel_launch(void* const* d_in, const int* in_sizes, int n_in,
                              void* d_out, int out_size, void* d_ws, size_t ws_size,
                              hipStream_t stream) {
  const float* inputs   = (const float*)d_in[0];
  const float* supports = (const float*)d_in[1];
  WSrc wsrc;
  wsrc.wg[0] = (const float*)d_in[2];  wsrc.wg[1] = (const float*)d_in[6];
  wsrc.wg[2] = (const float*)d_in[10]; wsrc.wg[3] = (const float*)d_in[14];
  wsrc.wc[0] = (const float*)d_in[4];  wsrc.wc[1] = (const float*)d_in[8];
  wsrc.wc[2] = (const float*)d_in[12]; wsrc.wc[3] = (const float*)d_in[16];
  const float* Bg[4] = { (const float*)d_in[3],  (const float*)d_in[7],
                         (const float*)d_in[11], (const float*)d_in[15] };
  const float* Bc[4] = { (const float*)d_in[5],  (const float*)d_in[9],
                         (const float*)d_in[13], (const float*)d_in[17] };
  const float* proj_w = (const float*)d_in[18];
  const float* proj_b = (const float*)d_in[19];
  float* out = (float*)d_out;

  char* p = (char*)d_ws;
  auto carve = [&](size_t bytes) { void* q = p; p += (bytes + 255) & ~(size_t)255; return q; };
  ushort* Bch  = (ushort*)carve((size_t)512 * 2048 * 2);
  ushort* zTh  = (ushort*)carve((size_t)32768 * 128 * 2);
  ushort* zTl  = (ushort*)carve((size_t)32768 * 128 * 2);
  ushort* Gh   = (ushort*)carve((size_t)8192 * 2048 * 2);
  float*  G0T  = (float*)carve((size_t)32768 * 128 * 4);
  float*  P    = (float*)carve((size_t)3 * 4194304 * 4);   // 48MB partials
  float*  U    = (float*)carve((size_t)2097152 * 4);
  float*  h0   = (float*)carve((size_t)2097152 * 4);
  float*  h1   = (float*)carve((size_t)2097152 * 4);
  float*  ybuf = (float*)carve((size_t)B_ * N_ * 4);
  ushort* Wbuf = (ushort*)carve((size_t)4 * 147456 * 2);
  ushort* STb  = (ushort*)U;     // overlay: STb (1MB) only needed during prep

  // h0 + h1 + ybuf contiguous -> one memset
  hipMemsetAsync(h0, 0, (size_t)2097152 * 4 * 2 + (size_t)B_ * N_ * 4, stream);

  stb_k<<<dim3(32, 32, 2), 256, 0, stream>>>(supports, Bch, STb);
  ssqm_k<<<dim3(4, 4, 2), 256, 0, stream>>>(Bch, STb, Bch);
  wprep_all_k<<<(4 * 147456 + 255) / 256, 256, 0, stream>>>(wsrc, Wbuf);

  auto cell = [&](int ci, int Cx, const float* x, int xmode, int t, float* h) {
    int C = Cx + 64;
    int K1 = (C + 31) & ~31;   // 96 or 128
    ushort* cw = Wbuf + (size_t)ci * 147456;
    ushort* Wgid_h = cw;          ushort* Wgid_l = cw + 16384;
    ushort* Wgd    = cw + 32768;
    ushort* Wcid_h = cw + 98304;  ushort* Wcid_l = cw + 106496;
    ushort* Wcd    = cw + 114688;
    packzT_k<<<128, 256, 0, stream>>>(x, xmode, t, Cx, C, h, zTh, zTl);
    g1_k<0><<<dim3(256, 5), 256, 0, stream>>>(Wgid_h, Wgid_l, Wgd, zTh, zTl, Gh, G0T, K1);
    ru1g_k<<<dim3(64, 4, 3), 256, 0, stream>>>(Gh, Bch, P);
    ru1f_k<<<4096, 256, 0, stream>>>(P, G0T, Bg[ci], h, U, zTh, zTl, Cx);
    g1_k<1><<<dim3(256, 3), 256, 0, stream>>>(Wcid_h, Wcid_l, Wcd, zTh, zTl, Gh, G0T, K1);
    ru2g_k<<<dim3(32, 4, 4), 256, 0, stream>>>(Gh, Bch, P);
    ru2f_k<<<2048, 256, 0, stream>>>(P, G0T, Bc[ci], U, h);
  };

  for (int t = 0; t < 12; ++t) {
    cell(0, 2, inputs, 0, t, h0);
    cell(1, 64, h0, 2, 0, h1);
  }
  for (int k = 0; k < 12; ++k) {
    cell(2, 1, ybuf, 1, 0, h0);
    cell(3, 64, h0, 2, 0, h1);
    proj_out_k<<<(B_ * N_ + 255) / 256, 256, 0, stream>>>(h1, proj_w, proj_b, ybuf, out, k);
  }
}

// Round 16
// 5294.104 us; speedup vs baseline: 1.2277x; 1.1767x over previous
//
#include <hip/hip_runtime.h>

#define B_ 64
#define N_ 512

typedef __attribute__((ext_vector_type(8))) short bf8_t;    // 8 bf16 (4 VGPRs)
typedef __attribute__((ext_vector_type(16))) float f16_t;   // 32x32 MFMA acc
typedef __attribute__((ext_vector_type(4))) float f4v_t;

#define MFMA32(a, b, c) __builtin_amdgcn_mfma_f32_32x32x16_bf16(a, b, c, 0, 0, 0)

__device__ __forceinline__ ushort f2bf(float x) {
  union { float f; unsigned u; } v; v.f = x;
  unsigned r = v.u + 0x7FFFu + ((v.u >> 16) & 1u);   // RNE
  return (ushort)(r >> 16);
}
__device__ __forceinline__ float bf2f(ushort h) {
  union { unsigned u; float f; } v; v.u = ((unsigned)h) << 16;
  return v.f;
}

__device__ __forceinline__ void gld16(const ushort* g, ushort* l) {
  __builtin_amdgcn_global_load_lds(
      (const __attribute__((address_space(1))) unsigned int*)(uintptr_t)g,
      (__attribute__((address_space(3))) unsigned int*)(uintptr_t)l,
      16, 0, 0);
}

// XCD-aware bijective swizzle (nwg must be divisible by 8)
__device__ __forceinline__ int xcd_logical(int nwg) {
  int lin = blockIdx.x + gridDim.x * (blockIdx.y + gridDim.y * blockIdx.z);
  return (lin & 7) * (nwg >> 3) + (lin >> 3);
}

// XOR swizzle (BK=32: 4x 16B slots/row; (r>>1)&3 spread → 2-way = free)
__device__ __forceinline__ int swz32(int r) { return (r >> 1) & 3; }

template <int ROWS, int THREADS>
__device__ __forceinline__ void stage_tile2(const ushort* g, int lda, int k0,
                                            ushort* l, int tid) {
  constexpr int RT = (ROWS * 32) / (THREADS * 8);
#pragma unroll
  for (int q = 0; q < RT; ++q) {
    int e  = q * THREADS * 8 + tid * 8;
    int r  = e >> 5;
    int c8 = (e >> 3) & 3;
    int g8 = c8 ^ swz32(r);
    gld16(g + (size_t)r * lda + k0 + g8 * 8, l + e);
  }
}

// C/D row-within-frag for 32x32: (r&3) + 8*(r>>2) + 4*hb
__device__ __forceinline__ int crow32(int r, int hb) {
  return (r & 3) + 8 * (r >> 2) + 4 * hb;
}

// ---------------------------------------------------------------------------
// 4-tile split-bf16 core (3-term): identity rows (f32-precision results).
// ---------------------------------------------------------------------------
__device__ __forceinline__ void core128(
    const ushort* Ah, const ushort* Al, int lda,
    const ushort* Bh, const ushort* Bl, int ldb,
    int K, ushort* lds, f16_t acc[2][2]) {
  constexpr int TILE = 128 * 32;
  constexpr int SSZ  = 4 * TILE;
  const int tid = threadIdx.x, lane = tid & 63, wave = tid >> 6;
  const int ar = lane & 31, hb = lane >> 5;
  const int wm = wave >> 1, wn = wave & 1;

  auto stage = [&](int buf, int k0) {
    ushort* lb = lds + buf * SSZ;
    stage_tile2<128, 256>(Ah, lda, k0, lb, tid);
    stage_tile2<128, 256>(Al, lda, k0, lb + TILE, tid);
    stage_tile2<128, 256>(Bh, ldb, k0, lb + 2 * TILE, tid);
    stage_tile2<128, 256>(Bl, ldb, k0, lb + 3 * TILE, tid);
  };

  const int nc = K >> 5;
  stage(0, 0);
  int buf = 0;
  for (int c = 0; c < nc; ++c) {
    __syncthreads();
    if (c + 1 < nc) stage(buf ^ 1, (c + 1) << 5);
    const ushort* lb = lds + buf * SSZ;
#pragma unroll
    for (int ks = 0; ks < 2; ++ks) {
      bf8_t ah[2], al[2], bh[2], bl[2];
#pragma unroll
      for (int i = 0; i < 2; ++i) {
        int r = wm * 64 + 32 * i + ar;
        int c8 = (ks * 2 + hb) ^ swz32(r);
        ah[i] = *(const bf8_t*)(lb + r * 32 + c8 * 8);
        al[i] = *(const bf8_t*)(lb + TILE + r * 32 + c8 * 8);
      }
#pragma unroll
      for (int j = 0; j < 2; ++j) {
        int r = wn * 64 + 32 * j + ar;
        int c8 = (ks * 2 + hb) ^ swz32(r);
        bh[j] = *(const bf8_t*)(lb + 2 * TILE + r * 32 + c8 * 8);
        bl[j] = *(const bf8_t*)(lb + 3 * TILE + r * 32 + c8 * 8);
      }
#pragma unroll
      for (int i = 0; i < 2; ++i)
#pragma unroll
        for (int j = 0; j < 2; ++j) {
          acc[i][j] = MFMA32(ah[i], bh[j], acc[i][j]);
          acc[i][j] = MFMA32(ah[i], bl[j], acc[i][j]);
          acc[i][j] = MFMA32(al[i], bh[j], acc[i][j]);
        }
    }
    buf ^= 1;
  }
}

// ---------------------------------------------------------------------------
// 2-tile core (1-term pure bf16), 128x128, 32KB LDS dbuf.
// ---------------------------------------------------------------------------
__device__ __forceinline__ void core128_1(
    const ushort* Ah, int lda,
    const ushort* Bh, int ldb,
    int K, ushort* lds, f16_t acc[2][2]) {
  constexpr int TILE = 128 * 32;
  constexpr int SSZ  = 2 * TILE;
  const int tid = threadIdx.x, lane = tid & 63, wave = tid >> 6;
  const int ar = lane & 31, hb = lane >> 5;
  const int wm = wave >> 1, wn = wave & 1;

  auto stage = [&](int buf, int k0) {
    ushort* lb = lds + buf * SSZ;
    stage_tile2<128, 256>(Ah, lda, k0, lb, tid);
    stage_tile2<128, 256>(Bh, ldb, k0, lb + TILE, tid);
  };

  const int nc = K >> 5;
  stage(0, 0);
  int buf = 0;
  for (int c = 0; c < nc; ++c) {
    __syncthreads();
    if (c + 1 < nc) stage(buf ^ 1, (c + 1) << 5);
    const ushort* lb = lds + buf * SSZ;
#pragma unroll
    for (int ks = 0; ks < 2; ++ks) {
      bf8_t ah[2], bh[2];
#pragma unroll
      for (int i = 0; i < 2; ++i) {
        int r = wm * 64 + 32 * i + ar;
        int c8 = (ks * 2 + hb) ^ swz32(r);
        ah[i] = *(const bf8_t*)(lb + r * 32 + c8 * 8);
      }
#pragma unroll
      for (int j = 0; j < 2; ++j) {
        int r = wn * 64 + 32 * j + ar;
        int c8 = (ks * 2 + hb) ^ swz32(r);
        bh[j] = *(const bf8_t*)(lb + TILE + r * 32 + c8 * 8);
      }
#pragma unroll
      for (int i = 0; i < 2; ++i)
#pragma unroll
        for (int j = 0; j < 2; ++j)
          acc[i][j] = MFMA32(ah[i], bh[j], acc[i][j]);
    }
    buf ^= 1;
  }
}

// ---------------------------------------------------------------------------
// Prep: S -> Bcat seg0/seg2 (bf16) + STb transposed bf16 copy
// ---------------------------------------------------------------------------
__global__ __launch_bounds__(256) void stb_k(const float* __restrict__ S,
                                             ushort* __restrict__ Bcat,
                                             ushort* __restrict__ STb) {
  __shared__ float tile[16][17];
  int s = blockIdx.z;
  int n0 = blockIdx.y * 16, m0 = blockIdx.x * 16;
  int tx = threadIdx.x & 15, ty = threadIdx.x >> 4;
  float v = S[(size_t)s * 262144 + (size_t)(n0 + ty) * 512 + m0 + tx];
  tile[ty][tx] = v;
  Bcat[(size_t)(n0 + ty) * 2048 + (size_t)(2 * s) * 512 + m0 + tx] = f2bf(v);
  __syncthreads();
  STb[(size_t)s * 262144 + (size_t)(m0 + ty) * 512 + n0 + tx] = f2bf(tile[tx][ty]);
}

// SS = S^2 via 1-term MFMA; writes Bcat seg(2s+1).
__global__ __launch_bounds__(256) void ssqm_k(const ushort* __restrict__ Bc,
                                              const ushort* __restrict__ STb,
                                              ushort* __restrict__ Bout) {
  __shared__ __attribute__((aligned(16))) ushort lds[2 * 2 * 128 * 32];
  int tid = threadIdx.x, lane = tid & 63, wave = tid >> 6;
  int wm = wave >> 1, wn = wave & 1, ar = lane & 31, hb = lane >> 5;
  int a = blockIdx.x, bm = blockIdx.y, s = blockIdx.z;
  f16_t acc[2][2] = {};
  core128_1(Bc + (size_t)(a * 128) * 2048 + (size_t)(2 * s) * 512, 2048,
            STb + (size_t)s * 262144 + (size_t)(bm * 128) * 512, 512,
            512, lds, acc);
#pragma unroll
  for (int i = 0; i < 2; ++i)
#pragma unroll
    for (int j = 0; j < 2; ++j) {
      int m_ = bm * 128 + wn * 64 + 32 * j + ar;
#pragma unroll
      for (int r = 0; r < 16; ++r) {
        int n_ = a * 128 + wm * 64 + 32 * i + crow32(r, hb);
        Bout[(size_t)n_ * 2048 + (size_t)(2 * s + 1) * 512 + m_] = f2bf(acc[i][j][r]);
      }
    }
}

// ---------------------------------------------------------------------------
// One-shot weight prep. Per-cell layout (ushort offsets):
// [gid_h 16384][gid_l 16384][gd 65536][cid_h 8192][cid_l 8192][cd 32768]
// ---------------------------------------------------------------------------
struct WSrc { const float* wg[4]; const float* wc[4]; };

__global__ __launch_bounds__(256) void wprep_all_k(WSrc src,
                                                   ushort* __restrict__ Wbuf) {
  int idx = blockIdx.x * 256 + threadIdx.x;
  if (idx >= 4 * 147456) return;
  int ci = idx / 147456, r = idx % 147456;
  int C = (ci == 0) ? 66 : (ci == 2) ? 65 : 128;
  const float* WG = src.wg[ci];
  const float* WC = src.wc[ci];
  ushort v;
  if (r < 32768) {
    int e = r & 16383, c = e & 127, d = e >> 7;
    float x = (c < C) ? WG[(size_t)c * 128 + d] : 0.f;
    ushort hh = f2bf(x);
    v = (r < 16384) ? hh : f2bf(x - bf2f(hh));
  } else if (r < 98304) {
    int e = r - 32768, c = e & 127, i = e >> 7;
    int t = 1 + (i >> 7), d = i & 127;
    v = (c < C) ? f2bf(WG[(size_t)(t * C + c) * 128 + d]) : (ushort)0;
  } else if (r < 114688) {
    int e = (r - 98304) & 8191, c = e & 127, d = e >> 7;
    float x = (c < C) ? WC[(size_t)c * 64 + d] : 0.f;
    ushort hh = f2bf(x);
    v = (r < 106496) ? hh : f2bf(x - bf2f(hh));
  } else {
    int e = r - 114688, c = e & 127, i = e >> 7;
    int t = 1 + (i >> 6), d = i & 63;
    v = (c < C) ? f2bf(WC[(size_t)(t * C + c) * 64 + d]) : (ushort)0;
  }
  Wbuf[idx] = v;
}

// ---------------------------------------------------------------------------
// packx: encoder x cols (0..1) of zT0 from inputs at time t. 1 thr/row.
// ---------------------------------------------------------------------------
__global__ __launch_bounds__(256) void packx_k(const float* __restrict__ xsrc,
                                               int t, ushort* __restrict__ Zh,
                                               ushort* __restrict__ Zl) {
  int jg = blockIdx.x * 256 + threadIdx.x;   // b*512+n
  int b = jg >> 9, n = jg & 511;
#pragma unroll
  for (int c = 0; c < 2; ++c) {
    float v = xsrc[((size_t)(b * 2 + c) * 512 + n) * 12 + t];
    ushort hh = f2bf(v);
    Zh[(size_t)jg * 96 + c] = hh;
    Zl[(size_t)jg * 96 + c] = f2bf(v - bf2f(hh));
  }
}

// encoder->decoder transition: zT0 := [0 | h0(64) | 0...] (96 cols)
__global__ __launch_bounds__(256) void trans_k(const float* __restrict__ hT0,
                                               ushort* __restrict__ Zh,
                                               ushort* __restrict__ Zl) {
  int idx = blockIdx.x * 256 + threadIdx.x;
  if (idx >= 32768 * 96) return;
  int col = idx % 96, row = idx / 96;
  float v = (col >= 1 && col <= 64) ? hT0[(size_t)row * 64 + (col - 1)] : 0.f;
  ushort hh = f2bf(v);
  Zh[(size_t)row * 96 + col] = hh;
  Zl[(size_t)row * 96 + col] = f2bf(v - bf2f(hh));
}

// ---------------------------------------------------------------------------
// Combined g1: mt < NMT -> 1-term diffusion rows (bf16 Gh);
// mt == NMT -> 3-term identity rows (f32 G0T). zs = zT row stride.
// ---------------------------------------------------------------------------
template <int MODE>
__global__ __launch_bounds__(256, 2) void g1_k(const ushort* __restrict__ Wih,
                                               const ushort* __restrict__ Wil,
                                               const ushort* __restrict__ Wd,
                                               const ushort* __restrict__ Zh,
                                               const ushort* __restrict__ Zl,
                                               ushort* __restrict__ Gh,
                                               float* __restrict__ G0T,
                                               int K, int zs) {
  __shared__ __attribute__((aligned(16))) ushort lds[2 * 4 * 128 * 32];
  constexpr int DR = (MODE == 0) ? 128 : 64;
  constexpr int NMT = (MODE == 0) ? 4 : 2;
  int tid = threadIdx.x, lane = tid & 63, wave = tid >> 6;
  int wm = wave >> 1, wn = wave & 1, ar = lane & 31, hb = lane >> 5;
  int L = xcd_logical(256 * (NMT + 1));
  int mt = L % (NMT + 1), nt = L / (NMT + 1);
  f16_t acc[2][2] = {};
  if (mt == NMT) {
    core128(Wih, Wil, 128,
            Zh + (size_t)nt * 128 * zs, Zl + (size_t)nt * 128 * zs, zs,
            K, lds, acc);
#pragma unroll
    for (int i = 0; i < 2; ++i)
#pragma unroll
      for (int j = 0; j < 2; ++j) {
        int jg = nt * 128 + wn * 64 + 32 * j + ar;
#pragma unroll
        for (int r = 0; r < 16; ++r) {
          int d = wm * 64 + 32 * i + crow32(r, hb);
          if (d >= DR) continue;
          G0T[(size_t)jg * DR + d] = acc[i][j][r];
        }
      }
  } else {
    core128_1(Wd + (size_t)mt * 128 * 128, 128,
              Zh + (size_t)nt * 128 * zs, zs,
              K, lds, acc);
#pragma unroll
    for (int i = 0; i < 2; ++i)
#pragma unroll
      for (int j = 0; j < 2; ++j) {
        int jg = nt * 128 + wn * 64 + 32 * j + ar;
        int b = jg >> 9, m = jg & 511;
#pragma unroll
        for (int r = 0; r < 16; ++r) {
          int ii = mt * 128 + wm * 64 + 32 * i + crow32(r, hb);
          int tt = ii / DR, d = ii % DR;
          Gh[((size_t)(b * DR + d)) * 2048 + (size_t)tt * 512 + m] = f2bf(acc[i][j][r]);
        }
      }
  }
}

// ---------------------------------------------------------------------------
// Gate diffusion GEMM (1-term, 2-tile), split-K kz=3 (768/768/512): -> P
// ---------------------------------------------------------------------------
__global__ __launch_bounds__(256, 3) void ru1g_k(const ushort* __restrict__ Gh,
                                                 const ushort* __restrict__ Bch,
                                                 float* __restrict__ P) {
  __shared__ __attribute__((aligned(16))) ushort lds[2 * 2 * 128 * 32];
  int tid = threadIdx.x, lane = tid & 63, wave = tid >> 6;
  int wm = wave >> 1, wn = wave & 1, ar = lane & 31, hb = lane >> 5;
  int L = xcd_logical(768);
  int mt = L & 3, nt = (L >> 2) & 63, kz = L >> 8;
  int k0 = kz * 768;
  int K  = (kz == 2) ? 512 : 768;
  f16_t acc[2][2] = {};
  core128_1(Bch + (size_t)mt * 128 * 2048 + k0, 2048,
            Gh + (size_t)nt * 128 * 2048 + k0, 2048,
            K, lds, acc);
  float* Pz = P + (size_t)kz * 4194304;
#pragma unroll
  for (int i = 0; i < 2; ++i)
#pragma unroll
    for (int j = 0; j < 2; ++j) {
      int R = nt * 128 + wn * 64 + 32 * j + ar;
      int b = R >> 7, d = R & 127;
#pragma unroll
      for (int r = 0; r < 16; ++r) {
        int node = mt * 128 + wm * 64 + 32 * i + crow32(r, hb);
        Pz[((size_t)b * 512 + node) * 128 + d] = acc[i][j][r];
      }
    }
}

// finish gate: sigmoid(P0+P1+P2+G0T+bg); d<64 -> r*h into zT; d>=64 -> u -> U
__global__ __launch_bounds__(256) void ru1f_k(const float* __restrict__ P,
                                              const float* __restrict__ G0T,
                                              const float* __restrict__ bg,
                                              const float* __restrict__ hT,
                                              float* __restrict__ U,
                                              ushort* __restrict__ Zh,
                                              ushort* __restrict__ Zl,
                                              int cx, int zs) {
  int i4 = blockIdx.x * 256 + threadIdx.x;
  if (i4 >= 1048576) return;
  int base = i4 * 4;
  int row = base >> 7, d = base & 127;
  f4v_t p0 = *(const f4v_t*)(P + base);
  f4v_t p1 = *(const f4v_t*)(P + 4194304 + base);
  f4v_t p2 = *(const f4v_t*)(P + 2 * 4194304 + base);
  f4v_t g0 = *(const f4v_t*)(G0T + base);
  if (d < 64) {
    f4v_t hv = *(const f4v_t*)(hT + (size_t)row * 64 + d);
#pragma unroll
    for (int e = 0; e < 4; ++e) {
      float s = 1.f / (1.f + expf(-(p0[e] + p1[e] + p2[e] + g0[e] + bg[d + e])));
      float rh = s * hv[e];
      ushort hh = f2bf(rh);
      Zh[(size_t)row * zs + cx + d + e] = hh;
      Zl[(size_t)row * zs + cx + d + e] = f2bf(rh - bf2f(hh));
    }
  } else {
    f4v_t uo;
#pragma unroll
    for (int e = 0; e < 4; ++e)
      uo[e] = 1.f / (1.f + expf(-(p0[e] + p1[e] + p2[e] + g0[e] + bg[d + e])));
    *(f4v_t*)(U + (size_t)row * 64 + (d - 64)) = uo;
  }
}

// ---------------------------------------------------------------------------
// Cand diffusion GEMM (1-term, 2-tile), split-K kz=4.
// ---------------------------------------------------------------------------
__global__ __launch_bounds__(256, 3) void ru2g_k(const ushort* __restrict__ Gh,
                                                 const ushort* __restrict__ Bch,
                                                 float* __restrict__ P) {
  __shared__ __attribute__((aligned(16))) ushort lds[2 * 2 * 128 * 32];
  int tid = threadIdx.x, lane = tid & 63, wave = tid >> 6;
  int wm = wave >> 1, wn = wave & 1, ar = lane & 31, hb = lane >> 5;
  int L = xcd_logical(512);
  int mt = L & 3, nt = (L >> 2) & 31, kz = L >> 7;
  f16_t acc[2][2] = {};
  core128_1(Bch + (size_t)mt * 128 * 2048 + kz * 512, 2048,
            Gh + (size_t)nt * 128 * 2048 + kz * 512, 2048,
            512, lds, acc);
  float* Pz = P + (size_t)kz * 2097152;
#pragma unroll
  for (int i = 0; i < 2; ++i)
#pragma unroll
    for (int j = 0; j < 2; ++j) {
      int R = nt * 128 + wn * 64 + 32 * j + ar;
      int b = R >> 6, d = R & 63;
#pragma unroll
      for (int r = 0; r < 16; ++r) {
        int node = mt * 128 + wm * 64 + 32 * i + crow32(r, hb);
        Pz[((size_t)b * 512 + node) * 64 + d] = acc[i][j][r];
      }
    }
}

// finish cand + h-update; threads the new h into zT buffers:
// self zT (cols sx..sx+63, stride zs) always; zT1 cols 0..63 if Z1h != null.
__global__ __launch_bounds__(256) void ru2f_k(const float* __restrict__ P,
                                              const float* __restrict__ G0c,
                                              const float* __restrict__ bc,
                                              const float* __restrict__ U,
                                              float* __restrict__ hT,
                                              ushort* __restrict__ Zsh,
                                              ushort* __restrict__ Zsl,
                                              int sx, int zs,
                                              ushort* __restrict__ Z1h,
                                              ushort* __restrict__ Z1l) {
  int i4 = blockIdx.x * 256 + threadIdx.x;
  if (i4 >= 524288) return;
  int base = i4 * 4;
  int row = base >> 6, d = base & 63;
  f4v_t p0 = *(const f4v_t*)(P + base);
  f4v_t p1 = *(const f4v_t*)(P + 2097152 + base);
  f4v_t p2 = *(const f4v_t*)(P + 2 * 2097152 + base);
  f4v_t p3 = *(const f4v_t*)(P + 3 * 2097152 + base);
  f4v_t g0 = *(const f4v_t*)(G0c + base);
  f4v_t uv = *(const f4v_t*)(U + base);
  f4v_t hv = *(const f4v_t*)(hT + base);
#pragma unroll
  for (int e = 0; e < 4; ++e) {
    float ct = tanhf(p0[e] + p1[e] + p2[e] + p3[e] + g0[e] + bc[d + e]);
    hv[e] = uv[e] * hv[e] + (1.f - uv[e]) * ct;
    ushort hh = f2bf(hv[e]);
    ushort ll = f2bf(hv[e] - bf2f(hh));
    Zsh[(size_t)row * zs + sx + d + e] = hh;
    Zsl[(size_t)row * zs + sx + d + e] = ll;
    if (Z1h) {
      Z1h[(size_t)row * 128 + d + e] = hh;
      Z1l[(size_t)row * 128 + d + e] = ll;
    }
  }
  *(f4v_t*)(hT + base) = hv;
}

// y = proj(h1) -> out[:, k] and zT0 col 0 (decoder x feed)
__global__ __launch_bounds__(256) void proj_out_k(const float* __restrict__ h1T,
                                                  const float* __restrict__ pw,
                                                  const float* __restrict__ pb,
                                                  float* __restrict__ out, int k,
                                                  ushort* __restrict__ Z0h,
                                                  ushort* __restrict__ Z0l) {
  int idx = blockIdx.x * blockDim.x + threadIdx.x;
  if (idx >= B_ * N_) return;
  float s = pb[0];
  const float* hrow = h1T + (size_t)idx * 64;
#pragma unroll
  for (int j = 0; j < 64; ++j)
    s = fmaf(pw[j], hrow[j], s);
  out[(size_t)idx * 12 + k] = s;
  ushort hh = f2bf(s);
  Z0h[(size_t)idx * 96] = hh;
  Z0l[(size_t)idx * 96] = f2bf(s - bf2f(hh));
}

extern "C" void kernel_launch(void* const* d_in, const int* in_sizes, int n_in,
                              void* d_out, int out_size, void* d_ws, size_t ws_size,
                              hipStream_t stream) {
  const float* inputs   = (const float*)d_in[0];
  const float* supports = (const float*)d_in[1];
  WSrc wsrc;
  wsrc.wg[0] = (const float*)d_in[2];  wsrc.wg[1] = (const float*)d_in[6];
  wsrc.wg[2] = (const float*)d_in[10]; wsrc.wg[3] = (const float*)d_in[14];
  wsrc.wc[0] = (const float*)d_in[4];  wsrc.wc[1] = (const float*)d_in[8];
  wsrc.wc[2] = (const float*)d_in[12]; wsrc.wc[3] = (const float*)d_in[16];
  const float* Bg[4] = { (const float*)d_in[3],  (const float*)d_in[7],
                         (const float*)d_in[11], (const float*)d_in[15] };
  const float* Bc[4] = { (const float*)d_in[5],  (const float*)d_in[9],
                         (const float*)d_in[13], (const float*)d_in[17] };
  const float* proj_w = (const float*)d_in[18];
  const float* proj_b = (const float*)d_in[19];
  float* out = (float*)d_out;

  char* p = (char*)d_ws;
  auto carve = [&](size_t bytes) { void* q = p; p += (bytes + 255) & ~(size_t)255; return q; };
  ushort* Bch  = (ushort*)carve((size_t)512 * 2048 * 2);
  ushort* Gh   = (ushort*)carve((size_t)8192 * 2048 * 2);
  float*  G0T  = (float*)carve((size_t)32768 * 128 * 4);
  float*  P    = (float*)carve((size_t)3 * 4194304 * 4);   // 48MB partials
  ushort* Wbuf = (ushort*)carve((size_t)4 * 147456 * 2);
  // ---- zeroed state zone (one memset): zT0 h/l, zT1 h/l, h0, h1 ----
  ushort* zT0h = (ushort*)carve((size_t)32768 * 96 * 2);
  ushort* zT0l = (ushort*)carve((size_t)32768 * 96 * 2);
  ushort* zT1h = (ushort*)carve((size_t)32768 * 128 * 2);
  ushort* zT1l = (ushort*)carve((size_t)32768 * 128 * 2);
  float*  h0   = (float*)carve((size_t)2097152 * 4);
  float*  h1   = (float*)carve((size_t)2097152 * 4);
  float*  U    = (float*)carve((size_t)2097152 * 4);
  ushort* STb  = (ushort*)U;     // overlay: STb (1MB) prep-only

  size_t zero_bytes = (size_t)32768 * 96 * 2 * 2 + (size_t)32768 * 128 * 2 * 2 +
                      (size_t)2097152 * 4 * 2;
  hipMemsetAsync(zT0h, 0, zero_bytes, stream);

  stb_k<<<dim3(32, 32, 2), 256, 0, stream>>>(supports, Bch, STb);
  ssqm_k<<<dim3(4, 4, 2), 256, 0, stream>>>(Bch, STb, Bch);
  wprep_all_k<<<(4 * 147456 + 255) / 256, 256, 0, stream>>>(wsrc, Wbuf);

  // cell runner: ci = cell type; zT/stride/cx wiring per type
  auto cell = [&](int ci) {
    ushort* cw = Wbuf + (size_t)ci * 147456;
    ushort* Wgid_h = cw;          ushort* Wgid_l = cw + 16384;
    ushort* Wgd    = cw + 32768;
    ushort* Wcid_h = cw + 98304;  ushort* Wcid_l = cw + 106496;
    ushort* Wcd    = cw + 114688;
    bool l0 = (ci == 0 || ci == 2);          // layer-0 cells use zT0
    ushort* Zh = l0 ? zT0h : zT1h;
    ushort* Zl = l0 ? zT0l : zT1l;
    int zs = l0 ? 96 : 128;
    int K1 = l0 ? 96 : 128;
    int cx = (ci == 0) ? 2 : (ci == 2) ? 1 : 64;
    float* h = l0 ? h0 : h1;
    g1_k<0><<<dim3(256, 5), 256, 0, stream>>>(Wgid_h, Wgid_l, Wgd, Zh, Zl, Gh, G0T, K1, zs);
    ru1g_k<<<dim3(64, 4, 3), 256, 0, stream>>>(Gh, Bch, P);
    ru1f_k<<<4096, 256, 0, stream>>>(P, G0T, Bg[ci], h, U, Zh, Zl, cx, zs);
    g1_k<1><<<dim3(256, 3), 256, 0, stream>>>(Wcid_h, Wcid_l, Wcd, Zh, Zl, Gh, G0T, K1, zs);
    ru2g_k<<<dim3(32, 4, 4), 256, 0, stream>>>(Gh, Bch, P);
    // h-threading: layer-0 writes self zT0 (sx=cx) + zT1 x-cols; layer-1 self only
    ru2f_k<<<2048, 256, 0, stream>>>(P, G0T, Bc[ci], U, h, Zh, Zl, cx, zs,
                                     l0 ? zT1h : nullptr, l0 ? zT1l : nullptr);
  };

  for (int t = 0; t < 12; ++t) {
    packx_k<<<128, 256, 0, stream>>>(inputs, t, zT0h, zT0l);
    cell(0);
    cell(1);
  }
  trans_k<<<(32768 * 96 + 255) / 256, 256, 0, stream>>>(h0, zT0h, zT0l);
  for (int k = 0; k < 12; ++k) {
    cell(2);
    cell(3);
    proj_out_k<<<128, 256, 0, stream>>>(h1, proj_w, proj_b, out, k, zT0h, zT0l);
  }
}

// Round 17
// 5231.675 us; speedup vs baseline: 1.2423x; 1.0119x over previous
//
#include <hip/hip_runtime.h>

#define B_ 64
#define N_ 512

typedef __attribute__((ext_vector_type(8))) short bf8_t;    // 8 bf16 (4 VGPRs)
typedef __attribute__((ext_vector_type(16))) float f16_t;   // 32x32 MFMA acc
typedef __attribute__((ext_vector_type(4))) float f4v_t;

#define MFMA32(a, b, c) __builtin_amdgcn_mfma_f32_32x32x16_bf16(a, b, c, 0, 0, 0)

__device__ __forceinline__ ushort f2bf(float x) {
  union { float f; unsigned u; } v; v.f = x;
  unsigned r = v.u + 0x7FFFu + ((v.u >> 16) & 1u);   // RNE
  return (ushort)(r >> 16);
}
__device__ __forceinline__ float bf2f(ushort h) {
  union { unsigned u; float f; } v; v.u = ((unsigned)h) << 16;
  return v.f;
}

__device__ __forceinline__ void gld16(const ushort* g, ushort* l) {
  __builtin_amdgcn_global_load_lds(
      (const __attribute__((address_space(1))) unsigned int*)(uintptr_t)g,
      (__attribute__((address_space(3))) unsigned int*)(uintptr_t)l,
      16, 0, 0);
}

// XCD-aware bijective swizzle (nwg must be divisible by 8)
__device__ __forceinline__ int xcd_logical(int nwg) {
  int lin = blockIdx.x + gridDim.x * (blockIdx.y + gridDim.y * blockIdx.z);
  return (lin & 7) * (nwg >> 3) + (lin >> 3);
}

// XOR swizzle (BK=32: 4x 16B slots/row; (r>>1)&3 spread → 2-way = free)
__device__ __forceinline__ int swz32(int r) { return (r >> 1) & 3; }

template <int ROWS, int THREADS>
__device__ __forceinline__ void stage_tile2(const ushort* g, int lda, int k0,
                                            ushort* l, int tid) {
  constexpr int RT = (ROWS * 32) / (THREADS * 8);
#pragma unroll
  for (int q = 0; q < RT; ++q) {
    int e  = q * THREADS * 8 + tid * 8;
    int r  = e >> 5;
    int c8 = (e >> 3) & 3;
    int g8 = c8 ^ swz32(r);
    gld16(g + (size_t)r * lda + k0 + g8 * 8, l + e);
  }
}

// C/D row-within-frag for 32x32: (r&3) + 8*(r>>2) + 4*hb
__device__ __forceinline__ int crow32(int r, int hb) {
  return (r & 3) + 8 * (r >> 2) + 4 * hb;
}

// ---------------------------------------------------------------------------
// 4-tile split-bf16 core (3-term): identity rows (f32-precision results).
// ---------------------------------------------------------------------------
__device__ __forceinline__ void core128(
    const ushort* Ah, const ushort* Al, int lda,
    const ushort* Bh, const ushort* Bl, int ldb,
    int K, ushort* lds, f16_t acc[2][2]) {
  constexpr int TILE = 128 * 32;
  constexpr int SSZ  = 4 * TILE;
  const int tid = threadIdx.x, lane = tid & 63, wave = tid >> 6;
  const int ar = lane & 31, hb = lane >> 5;
  const int wm = wave >> 1, wn = wave & 1;

  auto stage = [&](int buf, int k0) {
    ushort* lb = lds + buf * SSZ;
    stage_tile2<128, 256>(Ah, lda, k0, lb, tid);
    stage_tile2<128, 256>(Al, lda, k0, lb + TILE, tid);
    stage_tile2<128, 256>(Bh, ldb, k0, lb + 2 * TILE, tid);
    stage_tile2<128, 256>(Bl, ldb, k0, lb + 3 * TILE, tid);
  };

  const int nc = K >> 5;
  stage(0, 0);
  int buf = 0;
  for (int c = 0; c < nc; ++c) {
    __syncthreads();
    if (c + 1 < nc) stage(buf ^ 1, (c + 1) << 5);
    const ushort* lb = lds + buf * SSZ;
#pragma unroll
    for (int ks = 0; ks < 2; ++ks) {
      bf8_t ah[2], al[2], bh[2], bl[2];
#pragma unroll
      for (int i = 0; i < 2; ++i) {
        int r = wm * 64 + 32 * i + ar;
        int c8 = (ks * 2 + hb) ^ swz32(r);
        ah[i] = *(const bf8_t*)(lb + r * 32 + c8 * 8);
        al[i] = *(const bf8_t*)(lb + TILE + r * 32 + c8 * 8);
      }
#pragma unroll
      for (int j = 0; j < 2; ++j) {
        int r = wn * 64 + 32 * j + ar;
        int c8 = (ks * 2 + hb) ^ swz32(r);
        bh[j] = *(const bf8_t*)(lb + 2 * TILE + r * 32 + c8 * 8);
        bl[j] = *(const bf8_t*)(lb + 3 * TILE + r * 32 + c8 * 8);
      }
#pragma unroll
      for (int i = 0; i < 2; ++i)
#pragma unroll
        for (int j = 0; j < 2; ++j) {
          acc[i][j] = MFMA32(ah[i], bh[j], acc[i][j]);
          acc[i][j] = MFMA32(ah[i], bl[j], acc[i][j]);
          acc[i][j] = MFMA32(al[i], bh[j], acc[i][j]);
        }
    }
    buf ^= 1;
  }
}

// ---------------------------------------------------------------------------
// 2-tile core (1-term pure bf16), 128x128, 32KB LDS dbuf.
// ---------------------------------------------------------------------------
__device__ __forceinline__ void core128_1(
    const ushort* Ah, int lda,
    const ushort* Bh, int ldb,
    int K, ushort* lds, f16_t acc[2][2]) {
  constexpr int TILE = 128 * 32;
  constexpr int SSZ  = 2 * TILE;
  const int tid = threadIdx.x, lane = tid & 63, wave = tid >> 6;
  const int ar = lane & 31, hb = lane >> 5;
  const int wm = wave >> 1, wn = wave & 1;

  auto stage = [&](int buf, int k0) {
    ushort* lb = lds + buf * SSZ;
    stage_tile2<128, 256>(Ah, lda, k0, lb, tid);
    stage_tile2<128, 256>(Bh, ldb, k0, lb + TILE, tid);
  };

  const int nc = K >> 5;
  stage(0, 0);
  int buf = 0;
  for (int c = 0; c < nc; ++c) {
    __syncthreads();
    if (c + 1 < nc) stage(buf ^ 1, (c + 1) << 5);
    const ushort* lb = lds + buf * SSZ;
#pragma unroll
    for (int ks = 0; ks < 2; ++ks) {
      bf8_t ah[2], bh[2];
#pragma unroll
      for (int i = 0; i < 2; ++i) {
        int r = wm * 64 + 32 * i + ar;
        int c8 = (ks * 2 + hb) ^ swz32(r);
        ah[i] = *(const bf8_t*)(lb + r * 32 + c8 * 8);
      }
#pragma unroll
      for (int j = 0; j < 2; ++j) {
        int r = wn * 64 + 32 * j + ar;
        int c8 = (ks * 2 + hb) ^ swz32(r);
        bh[j] = *(const bf8_t*)(lb + TILE + r * 32 + c8 * 8);
      }
#pragma unroll
      for (int i = 0; i < 2; ++i)
#pragma unroll
        for (int j = 0; j < 2; ++j)
          acc[i][j] = MFMA32(ah[i], bh[j], acc[i][j]);
    }
    buf ^= 1;
  }
}

// ---------------------------------------------------------------------------
// Prep: S -> Bcat seg0/seg2 (bf16) + STb transposed bf16 copy
// ---------------------------------------------------------------------------
__global__ __launch_bounds__(256) void stb_k(const float* __restrict__ S,
                                             ushort* __restrict__ Bcat,
                                             ushort* __restrict__ STb) {
  __shared__ float tile[16][17];
  int s = blockIdx.z;
  int n0 = blockIdx.y * 16, m0 = blockIdx.x * 16;
  int tx = threadIdx.x & 15, ty = threadIdx.x >> 4;
  float v = S[(size_t)s * 262144 + (size_t)(n0 + ty) * 512 + m0 + tx];
  tile[ty][tx] = v;
  Bcat[(size_t)(n0 + ty) * 2048 + (size_t)(2 * s) * 512 + m0 + tx] = f2bf(v);
  __syncthreads();
  STb[(size_t)s * 262144 + (size_t)(m0 + ty) * 512 + n0 + tx] = f2bf(tile[tx][ty]);
}

// SS = S^2 via 1-term MFMA; writes Bcat seg(2s+1).
__global__ __launch_bounds__(256) void ssqm_k(const ushort* __restrict__ Bc,
                                              const ushort* __restrict__ STb,
                                              ushort* __restrict__ Bout) {
  __shared__ __attribute__((aligned(16))) ushort lds[2 * 2 * 128 * 32];
  int tid = threadIdx.x, lane = tid & 63, wave = tid >> 6;
  int wm = wave >> 1, wn = wave & 1, ar = lane & 31, hb = lane >> 5;
  int a = blockIdx.x, bm = blockIdx.y, s = blockIdx.z;
  f16_t acc[2][2] = {};
  core128_1(Bc + (size_t)(a * 128) * 2048 + (size_t)(2 * s) * 512, 2048,
            STb + (size_t)s * 262144 + (size_t)(bm * 128) * 512, 512,
            512, lds, acc);
#pragma unroll
  for (int i = 0; i < 2; ++i)
#pragma unroll
    for (int j = 0; j < 2; ++j) {
      int m_ = bm * 128 + wn * 64 + 32 * j + ar;
#pragma unroll
      for (int r = 0; r < 16; ++r) {
        int n_ = a * 128 + wm * 64 + 32 * i + crow32(r, hb);
        Bout[(size_t)n_ * 2048 + (size_t)(2 * s + 1) * 512 + m_] = f2bf(acc[i][j][r]);
      }
    }
}

// ---------------------------------------------------------------------------
// One-shot weight prep. Per-cell layout (ushort offsets):
// [gid_h 16384][gid_l 16384][gd 65536][cid_h 8192][cid_l 8192][cd 32768]
// ---------------------------------------------------------------------------
struct WSrc { const float* wg[4]; const float* wc[4]; };

__global__ __launch_bounds__(256) void wprep_all_k(WSrc src,
                                                   ushort* __restrict__ Wbuf) {
  int idx = blockIdx.x * 256 + threadIdx.x;
  if (idx >= 4 * 147456) return;
  int ci = idx / 147456, r = idx % 147456;
  int C = (ci == 0) ? 66 : (ci == 2) ? 65 : 128;
  const float* WG = src.wg[ci];
  const float* WC = src.wc[ci];
  ushort v;
  if (r < 32768) {
    int e = r & 16383, c = e & 127, d = e >> 7;
    float x = (c < C) ? WG[(size_t)c * 128 + d] : 0.f;
    ushort hh = f2bf(x);
    v = (r < 16384) ? hh : f2bf(x - bf2f(hh));
  } else if (r < 98304) {
    int e = r - 32768, c = e & 127, i = e >> 7;
    int t = 1 + (i >> 7), d = i & 127;
    v = (c < C) ? f2bf(WG[(size_t)(t * C + c) * 128 + d]) : (ushort)0;
  } else if (r < 114688) {
    int e = (r - 98304) & 8191, c = e & 127, d = e >> 7;
    float x = (c < C) ? WC[(size_t)c * 64 + d] : 0.f;
    ushort hh = f2bf(x);
    v = (r < 106496) ? hh : f2bf(x - bf2f(hh));
  } else {
    int e = r - 114688, c = e & 127, i = e >> 7;
    int t = 1 + (i >> 6), d = i & 63;
    v = (c < C) ? f2bf(WC[(size_t)(t * C + c) * 64 + d]) : (ushort)0;
  }
  Wbuf[idx] = v;
}

// packx: encoder x cols (0..1) of zT0 from inputs at time t (t=0 bootstrap).
__global__ __launch_bounds__(256) void packx_k(const float* __restrict__ xsrc,
                                               int t, ushort* __restrict__ Zh,
                                               ushort* __restrict__ Zl) {
  int jg = blockIdx.x * 256 + threadIdx.x;   // b*512+n
  int b = jg >> 9, n = jg & 511;
#pragma unroll
  for (int c = 0; c < 2; ++c) {
    float v = xsrc[((size_t)(b * 2 + c) * 512 + n) * 12 + t];
    ushort hh = f2bf(v);
    Zh[(size_t)jg * 96 + c] = hh;
    Zl[(size_t)jg * 96 + c] = f2bf(v - bf2f(hh));
  }
}

// encoder->decoder transition: zT0 := [0 | h0(64) | 0...] (96 cols)
__global__ __launch_bounds__(256) void trans_k(const float* __restrict__ hT0,
                                               ushort* __restrict__ Zh,
                                               ushort* __restrict__ Zl) {
  int idx = blockIdx.x * 256 + threadIdx.x;
  if (idx >= 32768 * 96) return;
  int col = idx % 96, row = idx / 96;
  float v = (col >= 1 && col <= 64) ? hT0[(size_t)row * 64 + (col - 1)] : 0.f;
  ushort hh = f2bf(v);
  Zh[(size_t)row * 96 + col] = hh;
  Zl[(size_t)row * 96 + col] = f2bf(v - bf2f(hh));
}

// ---------------------------------------------------------------------------
// Combined g1: mt < NMT -> 1-term diffusion rows (bf16 Gh);
// mt == NMT -> 3-term identity rows (f32 G0T). zs = zT row stride.
// ---------------------------------------------------------------------------
template <int MODE>
__global__ __launch_bounds__(256, 2) void g1_k(const ushort* __restrict__ Wih,
                                               const ushort* __restrict__ Wil,
                                               const ushort* __restrict__ Wd,
                                               const ushort* __restrict__ Zh,
                                               const ushort* __restrict__ Zl,
                                               ushort* __restrict__ Gh,
                                               float* __restrict__ G0T,
                                               int K, int zs) {
  __shared__ __attribute__((aligned(16))) ushort lds[2 * 4 * 128 * 32];
  constexpr int DR = (MODE == 0) ? 128 : 64;
  constexpr int NMT = (MODE == 0) ? 4 : 2;
  int tid = threadIdx.x, lane = tid & 63, wave = tid >> 6;
  int wm = wave >> 1, wn = wave & 1, ar = lane & 31, hb = lane >> 5;
  int L = xcd_logical(256 * (NMT + 1));
  int mt = L % (NMT + 1), nt = L / (NMT + 1);
  f16_t acc[2][2] = {};
  if (mt == NMT) {
    core128(Wih, Wil, 128,
            Zh + (size_t)nt * 128 * zs, Zl + (size_t)nt * 128 * zs, zs,
            K, lds, acc);
#pragma unroll
    for (int i = 0; i < 2; ++i)
#pragma unroll
      for (int j = 0; j < 2; ++j) {
        int jg = nt * 128 + wn * 64 + 32 * j + ar;
#pragma unroll
        for (int r = 0; r < 16; ++r) {
          int d = wm * 64 + 32 * i + crow32(r, hb);
          if (d >= DR) continue;
          G0T[(size_t)jg * DR + d] = acc[i][j][r];
        }
      }
  } else {
    core128_1(Wd + (size_t)mt * 128 * 128, 128,
              Zh + (size_t)nt * 128 * zs, zs,
              K, lds, acc);
#pragma unroll
    for (int i = 0; i < 2; ++i)
#pragma unroll
      for (int j = 0; j < 2; ++j) {
        int jg = nt * 128 + wn * 64 + 32 * j + ar;
        int b = jg >> 9, m = jg & 511;
#pragma unroll
        for (int r = 0; r < 16; ++r) {
          int ii = mt * 128 + wm * 64 + 32 * i + crow32(r, hb);
          int tt = ii / DR, d = ii % DR;
          Gh[((size_t)(b * DR + d)) * 2048 + (size_t)tt * 512 + m] = f2bf(acc[i][j][r]);
        }
      }
  }
}

// ---------------------------------------------------------------------------
// Gate diffusion GEMM (1-term, 2-tile), split-K kz=3 (768/768/512): -> P
// ---------------------------------------------------------------------------
__global__ __launch_bounds__(256, 3) void ru1g_k(const ushort* __restrict__ Gh,
                                                 const ushort* __restrict__ Bch,
                                                 float* __restrict__ P) {
  __shared__ __attribute__((aligned(16))) ushort lds[2 * 2 * 128 * 32];
  int tid = threadIdx.x, lane = tid & 63, wave = tid >> 6;
  int wm = wave >> 1, wn = wave & 1, ar = lane & 31, hb = lane >> 5;
  int L = xcd_logical(768);
  int mt = L & 3, nt = (L >> 2) & 63, kz = L >> 8;
  int k0 = kz * 768;
  int K  = (kz == 2) ? 512 : 768;
  f16_t acc[2][2] = {};
  core128_1(Bch + (size_t)mt * 128 * 2048 + k0, 2048,
            Gh + (size_t)nt * 128 * 2048 + k0, 2048,
            K, lds, acc);
  float* Pz = P + (size_t)kz * 4194304;
#pragma unroll
  for (int i = 0; i < 2; ++i)
#pragma unroll
    for (int j = 0; j < 2; ++j) {
      int R = nt * 128 + wn * 64 + 32 * j + ar;
      int b = R >> 7, d = R & 127;
#pragma unroll
      for (int r = 0; r < 16; ++r) {
        int node = mt * 128 + wm * 64 + 32 * i + crow32(r, hb);
        Pz[((size_t)b * 512 + node) * 128 + d] = acc[i][j][r];
      }
    }
}

// finish gate: sigmoid(P0+P1+P2+G0T+bg); d<64 -> r*h into zT; d>=64 -> u -> U
__global__ __launch_bounds__(256) void ru1f_k(const float* __restrict__ P,
                                              const float* __restrict__ G0T,
                                              const float* __restrict__ bg,
                                              const float* __restrict__ hT,
                                              float* __restrict__ U,
                                              ushort* __restrict__ Zh,
                                              ushort* __restrict__ Zl,
                                              int cx, int zs) {
  int i4 = blockIdx.x * 256 + threadIdx.x;
  if (i4 >= 1048576) return;
  int base = i4 * 4;
  int row = base >> 7, d = base & 127;
  f4v_t p0 = *(const f4v_t*)(P + base);
  f4v_t p1 = *(const f4v_t*)(P + 4194304 + base);
  f4v_t p2 = *(const f4v_t*)(P + 2 * 4194304 + base);
  f4v_t g0 = *(const f4v_t*)(G0T + base);
  if (d < 64) {
    f4v_t hv = *(const f4v_t*)(hT + (size_t)row * 64 + d);
#pragma unroll
    for (int e = 0; e < 4; ++e) {
      float s = 1.f / (1.f + expf(-(p0[e] + p1[e] + p2[e] + g0[e] + bg[d + e])));
      float rh = s * hv[e];
      ushort hh = f2bf(rh);
      Zh[(size_t)row * zs + cx + d + e] = hh;
      Zl[(size_t)row * zs + cx + d + e] = f2bf(rh - bf2f(hh));
    }
  } else {
    f4v_t uo;
#pragma unroll
    for (int e = 0; e < 4; ++e)
      uo[e] = 1.f / (1.f + expf(-(p0[e] + p1[e] + p2[e] + g0[e] + bg[d + e])));
    *(f4v_t*)(U + (size_t)row * 64 + (d - 64)) = uo;
  }
}

// ---------------------------------------------------------------------------
// Cand diffusion GEMM (1-term, 2-tile), split-K kz=4.
// ---------------------------------------------------------------------------
__global__ __launch_bounds__(256, 3) void ru2g_k(const ushort* __restrict__ Gh,
                                                 const ushort* __restrict__ Bch,
                                                 float* __restrict__ P) {
  __shared__ __attribute__((aligned(16))) ushort lds[2 * 2 * 128 * 32];
  int tid = threadIdx.x, lane = tid & 63, wave = tid >> 6;
  int wm = wave >> 1, wn = wave & 1, ar = lane & 31, hb = lane >> 5;
  int L = xcd_logical(512);
  int mt = L & 3, nt = (L >> 2) & 31, kz = L >> 7;
  f16_t acc[2][2] = {};
  core128_1(Bch + (size_t)mt * 128 * 2048 + kz * 512, 2048,
            Gh + (size_t)nt * 128 * 2048 + kz * 512, 2048,
            512, lds, acc);
  float* Pz = P + (size_t)kz * 2097152;
#pragma unroll
  for (int i = 0; i < 2; ++i)
#pragma unroll
    for (int j = 0; j < 2; ++j) {
      int R = nt * 128 + wn * 64 + 32 * j + ar;
      int b = R >> 6, d = R & 63;
#pragma unroll
      for (int r = 0; r < 16; ++r) {
        int node = mt * 128 + wm * 64 + 32 * i + crow32(r, hb);
        Pz[((size_t)b * 512 + node) * 64 + d] = acc[i][j][r];
      }
    }
}

// ---------------------------------------------------------------------------
// finish cand + h-update + state threading + optional x-feed / projection.
//   self zT (cols sx..sx+63, stride zs) always;
//   Z1h/Z1l: layer-0 -> zT1 x-cols (0..63);
//   xin/tnext: e1 -> write inputs(t+1) into zT0 cols 0..1;
//   pw/pb/out/k: d1 -> y = proj(h1) -> out[:,k] + zT0 col 0.
// ---------------------------------------------------------------------------
__global__ __launch_bounds__(256) void ru2f_k(const float* __restrict__ P,
                                              const float* __restrict__ G0c,
                                              const float* __restrict__ bc,
                                              const float* __restrict__ U,
                                              float* __restrict__ hT,
                                              ushort* __restrict__ Zsh,
                                              ushort* __restrict__ Zsl,
                                              int sx, int zs,
                                              ushort* __restrict__ Z1h,
                                              ushort* __restrict__ Z1l,
                                              ushort* __restrict__ Z0h,
                                              ushort* __restrict__ Z0l,
                                              const float* __restrict__ xin,
                                              int tnext,
                                              const float* __restrict__ pw,
                                              const float* __restrict__ pb,
                                              float* __restrict__ out, int k) {
  int i4 = blockIdx.x * 256 + threadIdx.x;
  if (i4 >= 524288) return;
  int base = i4 * 4;
  int row = base >> 6, d = base & 63;
  int q = i4 & 15;                      // quad index within row
  f4v_t p0 = *(const f4v_t*)(P + base);
  f4v_t p1 = *(const f4v_t*)(P + 2097152 + base);
  f4v_t p2 = *(const f4v_t*)(P + 2 * 2097152 + base);
  f4v_t p3 = *(const f4v_t*)(P + 3 * 2097152 + base);
  f4v_t g0 = *(const f4v_t*)(G0c + base);
  f4v_t uv = *(const f4v_t*)(U + base);
  f4v_t hv = *(const f4v_t*)(hT + base);
#pragma unroll
  for (int e = 0; e < 4; ++e) {
    float ct = tanhf(p0[e] + p1[e] + p2[e] + p3[e] + g0[e] + bc[d + e]);
    hv[e] = uv[e] * hv[e] + (1.f - uv[e]) * ct;
    ushort hh = f2bf(hv[e]);
    ushort ll = f2bf(hv[e] - bf2f(hh));
    Zsh[(size_t)row * zs + sx + d + e] = hh;
    Zsl[(size_t)row * zs + sx + d + e] = ll;
    if (Z1h) {
      Z1h[(size_t)row * 128 + d + e] = hh;
      Z1l[(size_t)row * 128 + d + e] = ll;
    }
  }
  *(f4v_t*)(hT + base) = hv;
  // e1: feed next-step x into zT0 cols 0..1
  if (xin && q == 0) {
    int b = row >> 9, n = row & 511;
#pragma unroll
    for (int c = 0; c < 2; ++c) {
      float v = xin[((size_t)(b * 2 + c) * 512 + n) * 12 + tnext];
      ushort hh = f2bf(v);
      Z0h[(size_t)row * 96 + c] = hh;
      Z0l[(size_t)row * 96 + c] = f2bf(v - bf2f(hh));
    }
  }
  // d1: output projection (16-lane group reduce)
  if (pw) {
    float s = 0.f;
#pragma unroll
    for (int e = 0; e < 4; ++e) s = fmaf(pw[d + e], hv[e], s);
    s += __shfl_xor(s, 1);
    s += __shfl_xor(s, 2);
    s += __shfl_xor(s, 4);
    s += __shfl_xor(s, 8);
    if (q == 0) {
      float y = s + pb[0];
      out[(size_t)row * 12 + k] = y;
      ushort hh = f2bf(y);
      Z0h[(size_t)row * 96] = hh;
      Z0l[(size_t)row * 96] = f2bf(y - bf2f(hh));
    }
  }
}

extern "C" void kernel_launch(void* const* d_in, const int* in_sizes, int n_in,
                              void* d_out, int out_size, void* d_ws, size_t ws_size,
                              hipStream_t stream) {
  const float* inputs   = (const float*)d_in[0];
  const float* supports = (const float*)d_in[1];
  WSrc wsrc;
  wsrc.wg[0] = (const float*)d_in[2];  wsrc.wg[1] = (const float*)d_in[6];
  wsrc.wg[2] = (const float*)d_in[10]; wsrc.wg[3] = (const float*)d_in[14];
  wsrc.wc[0] = (const float*)d_in[4];  wsrc.wc[1] = (const float*)d_in[8];
  wsrc.wc[2] = (const float*)d_in[12]; wsrc.wc[3] = (const float*)d_in[16];
  const float* Bg[4] = { (const float*)d_in[3],  (const float*)d_in[7],
                         (const float*)d_in[11], (const float*)d_in[15] };
  const float* Bc[4] = { (const float*)d_in[5],  (const float*)d_in[9],
                         (const float*)d_in[13], (const float*)d_in[17] };
  const float* proj_w = (const float*)d_in[18];
  const float* proj_b = (const float*)d_in[19];
  float* out = (float*)d_out;

  char* p = (char*)d_ws;
  auto carve = [&](size_t bytes) { void* q = p; p += (bytes + 255) & ~(size_t)255; return q; };
  ushort* Bch  = (ushort*)carve((size_t)512 * 2048 * 2);
  ushort* Gh   = (ushort*)carve((size_t)8192 * 2048 * 2);
  float*  G0T  = (float*)carve((size_t)32768 * 128 * 4);
  float*  P    = (float*)carve((size_t)3 * 4194304 * 4);   // 48MB partials
  ushort* Wbuf = (ushort*)carve((size_t)4 * 147456 * 2);
  // ---- zeroed state zone (one memset): zT0 h/l, zT1 h/l, h0, h1 ----
  ushort* zT0h = (ushort*)carve((size_t)32768 * 96 * 2);
  ushort* zT0l = (ushort*)carve((size_t)32768 * 96 * 2);
  ushort* zT1h = (ushort*)carve((size_t)32768 * 128 * 2);
  ushort* zT1l = (ushort*)carve((size_t)32768 * 128 * 2);
  float*  h0   = (float*)carve((size_t)2097152 * 4);
  float*  h1   = (float*)carve((size_t)2097152 * 4);
  float*  U    = (float*)carve((size_t)2097152 * 4);
  ushort* STb  = (ushort*)U;     // overlay: STb (1MB) prep-only

  size_t zero_bytes = (size_t)32768 * 96 * 2 * 2 + (size_t)32768 * 128 * 2 * 2 +
                      (size_t)2097152 * 4 * 2;
  hipMemsetAsync(zT0h, 0, zero_bytes, stream);

  stb_k<<<dim3(32, 32, 2), 256, 0, stream>>>(supports, Bch, STb);
  ssqm_k<<<dim3(4, 4, 2), 256, 0, stream>>>(Bch, STb, Bch);
  wprep_all_k<<<(4 * 147456 + 255) / 256, 256, 0, stream>>>(wsrc, Wbuf);

  // cell runner; ci = cell type 0..3 (e0,e1,d0,d1). tnext >= 0 -> e1 x-feed;
  // doproj -> d1 projection fused into ru2f.
  auto cell = [&](int ci, int tnext, bool doproj, int k) {
    ushort* cw = Wbuf + (size_t)ci * 147456;
    ushort* Wgid_h = cw;          ushort* Wgid_l = cw + 16384;
    ushort* Wgd    = cw + 32768;
    ushort* Wcid_h = cw + 98304;  ushort* Wcid_l = cw + 106496;
    ushort* Wcd    = cw + 114688;
    bool l0 = (ci == 0 || ci == 2);
    ushort* Zh = l0 ? zT0h : zT1h;
    ushort* Zl = l0 ? zT0l : zT1l;
    int zs = l0 ? 96 : 128;
    int K1 = l0 ? 96 : 128;
    int cx = (ci == 0) ? 2 : (ci == 2) ? 1 : 64;
    float* h = l0 ? h0 : h1;
    g1_k<0><<<dim3(256, 5), 256, 0, stream>>>(Wgid_h, Wgid_l, Wgd, Zh, Zl, Gh, G0T, K1, zs);
    ru1g_k<<<dim3(64, 4, 3), 256, 0, stream>>>(Gh, Bch, P);
    ru1f_k<<<4096, 256, 0, stream>>>(P, G0T, Bg[ci], h, U, Zh, Zl, cx, zs);
    g1_k<1><<<dim3(256, 3), 256, 0, stream>>>(Wcid_h, Wcid_l, Wcd, Zh, Zl, Gh, G0T, K1, zs);
    ru2g_k<<<dim3(32, 4, 4), 256, 0, stream>>>(Gh, Bch, P);
    ru2f_k<<<2048, 256, 0, stream>>>(P, G0T, Bc[ci], U, h, Zh, Zl, cx, zs,
                                     l0 ? zT1h : nullptr, l0 ? zT1l : nullptr,
                                     zT0h, zT0l,
                                     (tnext >= 0) ? inputs : nullptr, tnext,
                                     doproj ? proj_w : nullptr, proj_b, out, k);
  };

  packx_k<<<128, 256, 0, stream>>>(inputs, 0, zT0h, zT0l);
  for (int t = 0; t < 12; ++t) {
    cell(0, -1, false, 0);
    cell(1, (t < 11) ? t + 1 : -1, false, 0);
  }
  trans_k<<<(32768 * 96 + 255) / 256, 256, 0, stream>>>(h0, zT0h, zT0l);
  for (int k = 0; k < 12; ++k) {
    cell(2, -1, false, 0);
    cell(3, -1, true, k);
  }
}